// Round 1
// baseline (1273.198 us; speedup 1.0000x reference)
//
#include <hip/hip_runtime.h>
#include <math.h>

// ---------------- CSR build ----------------

__global__ void hist_kernel(const int* __restrict__ dst, int* __restrict__ cnt, int n_edges) {
    int e = blockIdx.x * blockDim.x + threadIdx.x;
    if (e < n_edges) atomicAdd(&cnt[dst[e]], 1);
}

// single-block chunked exclusive scan -> rowptr (n+1 entries)
__global__ __launch_bounds__(1024) void scan_kernel(const int* __restrict__ cnt,
                                                    int* __restrict__ rowptr, int n) {
    int tid = threadIdx.x;
    int chunk = (n + 1023) >> 10;
    int s0 = tid * chunk;
    int s1 = min(s0 + chunk, n);
    int sum = 0;
    for (int i = s0; i < s1; ++i) sum += cnt[i];

    int lane = tid & 63, wave = tid >> 6;
    int v = sum;
#pragma unroll
    for (int off = 1; off < 64; off <<= 1) {
        int t = __shfl_up(v, off, 64);
        if (lane >= off) v += t;
    }
    __shared__ int wsum[16], woff[16];
    if (lane == 63) wsum[wave] = v;
    __syncthreads();
    if (wave == 0 && lane < 16) {
        int wv = wsum[lane];
#pragma unroll
        for (int off = 1; off < 16; off <<= 1) {
            int t = __shfl_up(wv, off, 64);
            if (lane >= off) wv += t;
        }
        woff[lane] = wv - wsum[lane];  // exclusive prefix of wave sums
    }
    __syncthreads();
    int excl = woff[wave] + (v - sum);  // exclusive prefix for this thread's chunk
    if (tid == 0) rowptr[0] = 0;
    int run = excl;
    for (int i = s0; i < s1; ++i) {
        run += cnt[i];
        rowptr[i + 1] = run;
    }
}

__global__ void invdeg_copy_kernel(const int* __restrict__ cnt, const int* __restrict__ rowptr,
                                   float* __restrict__ inv_deg, int* __restrict__ cursor, int n) {
    int i = blockIdx.x * blockDim.x + threadIdx.x;
    if (i < n) {
        int c = cnt[i];
        inv_deg[i] = c > 0 ? 1.0f / (float)c : 0.0f;
        cursor[i] = rowptr[i];
    }
}

__global__ void scatter_kernel(const int* __restrict__ src, const int* __restrict__ dst,
                               int* __restrict__ cursor, int* __restrict__ ssrc, int n_edges) {
    int e = blockIdx.x * blockDim.x + threadIdx.x;
    if (e < n_edges) {
        int p = atomicAdd(&cursor[dst[e]], 1);
        ssrc[p] = src[e];
    }
}

// ---------------- mean aggregation (gather over CSR) ----------------
// 8 nodes per 256-thread block; 32 lanes x float4 cover the 128 features.
__global__ __launch_bounds__(256) void agg_kernel(const float4* __restrict__ h4,
                                                  const int* __restrict__ rowptr,
                                                  const int* __restrict__ ssrc,
                                                  const float* __restrict__ inv_deg,
                                                  float4* __restrict__ agg4, int n_nodes) {
    int tid = threadIdx.x;
    int d = tid & 31;
    int n = blockIdx.x * 8 + (tid >> 5);
    if (n >= n_nodes) return;
    int e0 = rowptr[n], e1 = rowptr[n + 1];
    float4 acc = make_float4(0.f, 0.f, 0.f, 0.f);
    for (int e = e0; e < e1; ++e) {
        int s = ssrc[e];
        float4 vv = h4[(size_t)s * 32 + d];
        acc.x += vv.x; acc.y += vv.y; acc.z += vv.z; acc.w += vv.w;
    }
    float w = inv_deg[n];
    acc.x *= w; acc.y *= w; acc.z *= w; acc.w *= w;
    agg4[(size_t)n * 32 + d] = acc;
}

// ---------------- fused GEMM: out = relu([agg|h] @ [Wl;Wr] + b), dout=128 ----------------
// 32 rows/block, 4x4 register tile/thread, A-tile in LDS (broadcast reads), W from L2.
__global__ __launch_bounds__(256) void gemm128_kernel(const float* __restrict__ agg,
                                                      const float* __restrict__ h,
                                                      const float* __restrict__ Wl,
                                                      const float* __restrict__ Wr,
                                                      const float* __restrict__ bias,
                                                      float* __restrict__ out, int n_nodes) {
    __shared__ float As[32][256];
    int tid = threadIdx.x;
    int n0 = blockIdx.x * 32;
    for (int idx = tid; idx < 2048; idx += 256) {
        int row = idx >> 6;
        int k4 = idx & 63;
        int n = n0 + row;
        float4 v = make_float4(0.f, 0.f, 0.f, 0.f);
        if (n < n_nodes) {
            v = (k4 < 32) ? ((const float4*)agg)[(size_t)n * 32 + k4]
                          : ((const float4*)h)[(size_t)n * 32 + (k4 - 32)];
        }
        *(float4*)&As[row][k4 * 4] = v;
    }
    __syncthreads();

    int col0 = (tid & 31) * 4;
    int row0 = (tid >> 5) * 4;
    float acc[4][4];
#pragma unroll
    for (int r = 0; r < 4; ++r)
#pragma unroll
        for (int c = 0; c < 4; ++c) acc[r][c] = 0.f;

    for (int k = 0; k < 128; ++k) {
        float4 w = *(const float4*)&Wl[k * 128 + col0];
#pragma unroll
        for (int r = 0; r < 4; ++r) {
            float a = As[row0 + r][k];
            acc[r][0] += a * w.x; acc[r][1] += a * w.y;
            acc[r][2] += a * w.z; acc[r][3] += a * w.w;
        }
    }
    for (int k = 0; k < 128; ++k) {
        float4 w = *(const float4*)&Wr[k * 128 + col0];
#pragma unroll
        for (int r = 0; r < 4; ++r) {
            float a = As[row0 + r][k + 128];
            acc[r][0] += a * w.x; acc[r][1] += a * w.y;
            acc[r][2] += a * w.z; acc[r][3] += a * w.w;
        }
    }

    float4 b = *(const float4*)&bias[col0];
#pragma unroll
    for (int r = 0; r < 4; ++r) {
        int n = n0 + row0 + r;
        if (n < n_nodes) {
            float4 o;
            o.x = fmaxf(acc[r][0] + b.x, 0.f);
            o.y = fmaxf(acc[r][1] + b.y, 0.f);
            o.z = fmaxf(acc[r][2] + b.z, 0.f);
            o.w = fmaxf(acc[r][3] + b.w, 0.f);
            *(float4*)&out[(size_t)n * 128 + col0] = o;
        }
    }
}

// ---------------- layer 2: dout=47 (padded to 64) + fused log_softmax ----------------
// 32 rows/block; thread tile 4 rows x 2 cols; one row's 64 padded cols live in one
// 32-lane half-wave -> width-32 shuffle reductions for max / sum(exp).
__global__ __launch_bounds__(256) void gemm_out_kernel(const float* __restrict__ agg,
                                                       const float* __restrict__ h,
                                                       const float* __restrict__ Wl,
                                                       const float* __restrict__ Wr,
                                                       const float* __restrict__ bias,
                                                       float* __restrict__ out, int n_nodes) {
    __shared__ float As[32][256];
    int tid = threadIdx.x;
    int n0 = blockIdx.x * 32;
    for (int idx = tid; idx < 2048; idx += 256) {
        int row = idx >> 6;
        int k4 = idx & 63;
        int n = n0 + row;
        float4 v = make_float4(0.f, 0.f, 0.f, 0.f);
        if (n < n_nodes) {
            v = (k4 < 32) ? ((const float4*)agg)[(size_t)n * 32 + k4]
                          : ((const float4*)h)[(size_t)n * 32 + (k4 - 32)];
        }
        *(float4*)&As[row][k4 * 4] = v;
    }
    __syncthreads();

    int col0 = (tid & 31) * 2;
    int row0 = (tid >> 5) * 4;
    bool c0ok = col0 < 47, c1ok = (col0 + 1) < 47;
    float acc[4][2];
#pragma unroll
    for (int r = 0; r < 4; ++r) { acc[r][0] = 0.f; acc[r][1] = 0.f; }

    for (int k = 0; k < 128; ++k) {
        float w0 = c0ok ? Wl[k * 47 + col0] : 0.f;
        float w1 = c1ok ? Wl[k * 47 + col0 + 1] : 0.f;
#pragma unroll
        for (int r = 0; r < 4; ++r) {
            float a = As[row0 + r][k];
            acc[r][0] += a * w0; acc[r][1] += a * w1;
        }
    }
    for (int k = 0; k < 128; ++k) {
        float w0 = c0ok ? Wr[k * 47 + col0] : 0.f;
        float w1 = c1ok ? Wr[k * 47 + col0 + 1] : 0.f;
#pragma unroll
        for (int r = 0; r < 4; ++r) {
            float a = As[row0 + r][k + 128];
            acc[r][0] += a * w0; acc[r][1] += a * w1;
        }
    }

    float b0 = c0ok ? bias[col0] : 0.f;
    float b1 = c1ok ? bias[col0 + 1] : 0.f;
#pragma unroll
    for (int r = 0; r < 4; ++r) {
        float v0 = c0ok ? acc[r][0] + b0 : -INFINITY;
        float v1 = c1ok ? acc[r][1] + b1 : -INFINITY;
        float m = fmaxf(v0, v1);
#pragma unroll
        for (int offx = 16; offx >= 1; offx >>= 1)
            m = fmaxf(m, __shfl_xor(m, offx, 32));
        float s = (c0ok ? __expf(v0 - m) : 0.f) + (c1ok ? __expf(v1 - m) : 0.f);
#pragma unroll
        for (int offx = 16; offx >= 1; offx >>= 1)
            s += __shfl_xor(s, offx, 32);
        float ls = __logf(s);
        int n = n0 + row0 + r;
        if (n < n_nodes) {
            if (c0ok) out[(size_t)n * 47 + col0] = v0 - m - ls;
            if (c1ok) out[(size_t)n * 47 + col0 + 1] = v1 - m - ls;
        }
    }
}

// ---------------- launch ----------------

extern "C" void kernel_launch(void* const* d_in, const int* in_sizes, int n_in,
                              void* d_out, int out_size, void* d_ws, size_t ws_size,
                              hipStream_t stream) {
    const float* x   = (const float*)d_in[0];
    const int*   src = (const int*)d_in[1];
    const int*   dst = (const int*)d_in[2];
    const float* Wl0 = (const float*)d_in[3];
    const float* bl0 = (const float*)d_in[4];
    const float* Wr0 = (const float*)d_in[5];
    const float* Wl1 = (const float*)d_in[6];
    const float* bl1 = (const float*)d_in[7];
    const float* Wr1 = (const float*)d_in[8];
    const float* Wl2 = (const float*)d_in[9];
    const float* bl2 = (const float*)d_in[10];
    const float* Wr2 = (const float*)d_in[11];
    float* out = (float*)d_out;

    int N = in_sizes[0] / 128;
    int E = in_sizes[1];

    char* ws = (char*)d_ws;
    size_t off = 0;
    auto alloc = [&](size_t bytes) -> char* {
        char* p = ws + off;
        off += (bytes + 255) & ~(size_t)255;
        return p;
    };
    int*   cnt    = (int*)alloc((size_t)N * 4);
    int*   rowptr = (int*)alloc((size_t)(N + 1) * 4);
    int*   cursor = (int*)alloc((size_t)N * 4);
    float* invd   = (float*)alloc((size_t)N * 4);
    int*   ssrc   = (int*)alloc((size_t)E * 4);
    float* aggb   = (float*)alloc((size_t)N * 128 * 4);
    float* hbuf   = (float*)alloc((size_t)N * 128 * 4);

    hipMemsetAsync(cnt, 0, (size_t)N * 4, stream);
    hist_kernel<<<(E + 255) / 256, 256, 0, stream>>>(dst, cnt, E);
    scan_kernel<<<1, 1024, 0, stream>>>(cnt, rowptr, N);
    invdeg_copy_kernel<<<(N + 255) / 256, 256, 0, stream>>>(cnt, rowptr, invd, cursor, N);
    scatter_kernel<<<(E + 255) / 256, 256, 0, stream>>>(src, dst, cursor, ssrc, E);

    int aggGrid  = (N + 7) / 8;
    int gemmGrid = (N + 31) / 32;

    // layer 0: x -> hbuf
    agg_kernel<<<aggGrid, 256, 0, stream>>>((const float4*)x, rowptr, ssrc, invd,
                                            (float4*)aggb, N);
    gemm128_kernel<<<gemmGrid, 256, 0, stream>>>(aggb, x, Wl0, Wr0, bl0, hbuf, N);

    // layer 1: hbuf -> hbuf (in-place safe: each block stages its rows in LDS first)
    agg_kernel<<<aggGrid, 256, 0, stream>>>((const float4*)hbuf, rowptr, ssrc, invd,
                                            (float4*)aggb, N);
    gemm128_kernel<<<gemmGrid, 256, 0, stream>>>(aggb, hbuf, Wl1, Wr1, bl1, hbuf, N);

    // layer 2: hbuf -> out (fused log_softmax)
    agg_kernel<<<aggGrid, 256, 0, stream>>>((const float4*)hbuf, rowptr, ssrc, invd,
                                            (float4*)aggb, N);
    gemm_out_kernel<<<gemmGrid, 256, 0, stream>>>(aggb, hbuf, Wl2, Wr2, bl2, out, N);
}

// Round 2
// 1090.465 us; speedup vs baseline: 1.1676x; 1.1676x over previous
//
#include <hip/hip_runtime.h>
#include <math.h>

// ---------------- CSR build ----------------

__global__ void hist_kernel(const int* __restrict__ dst, int* __restrict__ cnt, int n_edges) {
    int e = blockIdx.x * blockDim.x + threadIdx.x;
    if (e < n_edges) atomicAdd(&cnt[dst[e]], 1);
}

// single-block chunked exclusive scan -> rowptr (n+1 entries)
__global__ __launch_bounds__(1024) void scan_kernel(const int* __restrict__ cnt,
                                                    int* __restrict__ rowptr, int n) {
    int tid = threadIdx.x;
    int chunk = (n + 1023) >> 10;
    int s0 = tid * chunk;
    int s1 = min(s0 + chunk, n);
    int sum = 0;
    for (int i = s0; i < s1; ++i) sum += cnt[i];

    int lane = tid & 63, wave = tid >> 6;
    int v = sum;
#pragma unroll
    for (int off = 1; off < 64; off <<= 1) {
        int t = __shfl_up(v, off, 64);
        if (lane >= off) v += t;
    }
    __shared__ int wsum[16], woff[16];
    if (lane == 63) wsum[wave] = v;
    __syncthreads();
    if (wave == 0 && lane < 16) {
        int wv = wsum[lane];
#pragma unroll
        for (int off = 1; off < 16; off <<= 1) {
            int t = __shfl_up(wv, off, 64);
            if (lane >= off) wv += t;
        }
        woff[lane] = wv - wsum[lane];
    }
    __syncthreads();
    int excl = woff[wave] + (v - sum);
    if (tid == 0) rowptr[0] = 0;
    int run = excl;
    for (int i = s0; i < s1; ++i) {
        run += cnt[i];
        rowptr[i + 1] = run;
    }
}

__global__ void invdeg_copy_kernel(const int* __restrict__ cnt, const int* __restrict__ rowptr,
                                   float* __restrict__ inv_deg, int* __restrict__ cursor, int n) {
    int i = blockIdx.x * blockDim.x + threadIdx.x;
    if (i < n) {
        int c = cnt[i];
        inv_deg[i] = c > 0 ? 1.0f / (float)c : 0.0f;
        cursor[i] = rowptr[i];
    }
}

__global__ void scatter_kernel(const int* __restrict__ src, const int* __restrict__ dst,
                               int* __restrict__ cursor, int* __restrict__ ssrc, int n_edges) {
    int e = blockIdx.x * blockDim.x + threadIdx.x;
    if (e < n_edges) {
        int p = atomicAdd(&cursor[dst[e]], 1);
        ssrc[p] = src[e];
    }
}

// ---------------- mean aggregation (gather over CSR), layers 0/1 ----------------
// 8 nodes per 256-thread block; 32 lanes x float4 cover the 128 features.
// Edge loop unrolled x2 for memory-level parallelism (ssrc->gather is a chained load).
__global__ __launch_bounds__(256) void agg_kernel(const float4* __restrict__ h4,
                                                  const int* __restrict__ rowptr,
                                                  const int* __restrict__ ssrc,
                                                  const float* __restrict__ inv_deg,
                                                  float4* __restrict__ agg4, int n_nodes) {
    int tid = threadIdx.x;
    int d = tid & 31;
    int n = blockIdx.x * 8 + (tid >> 5);
    if (n >= n_nodes) return;
    int e0 = rowptr[n], e1 = rowptr[n + 1];
    float4 acc = make_float4(0.f, 0.f, 0.f, 0.f);
    int e = e0;
    for (; e + 1 < e1; e += 2) {
        int s0 = ssrc[e];
        int s1 = ssrc[e + 1];
        float4 v0 = h4[(size_t)s0 * 32 + d];
        float4 v1 = h4[(size_t)s1 * 32 + d];
        acc.x += v0.x; acc.y += v0.y; acc.z += v0.z; acc.w += v0.w;
        acc.x += v1.x; acc.y += v1.y; acc.z += v1.z; acc.w += v1.w;
    }
    if (e < e1) {
        int s = ssrc[e];
        float4 vv = h4[(size_t)s * 32 + d];
        acc.x += vv.x; acc.y += vv.y; acc.z += vv.z; acc.w += vv.w;
    }
    float w = inv_deg[n];
    acc.x *= w; acc.y *= w; acc.z *= w; acc.w *= w;
    agg4[(size_t)n * 32 + d] = acc;
}

// ---------------- fused GEMM: out = relu([agg|h] @ [Wl;Wr] + b), dout=128 ----------------
__global__ __launch_bounds__(256) void gemm128_kernel(const float* __restrict__ agg,
                                                      const float* __restrict__ h,
                                                      const float* __restrict__ Wl,
                                                      const float* __restrict__ Wr,
                                                      const float* __restrict__ bias,
                                                      float* __restrict__ out, int n_nodes) {
    __shared__ float As[32][256];
    int tid = threadIdx.x;
    int n0 = blockIdx.x * 32;
    for (int idx = tid; idx < 2048; idx += 256) {
        int row = idx >> 6;
        int k4 = idx & 63;
        int n = n0 + row;
        float4 v = make_float4(0.f, 0.f, 0.f, 0.f);
        if (n < n_nodes) {
            v = (k4 < 32) ? ((const float4*)agg)[(size_t)n * 32 + k4]
                          : ((const float4*)h)[(size_t)n * 32 + (k4 - 32)];
        }
        *(float4*)&As[row][k4 * 4] = v;
    }
    __syncthreads();

    int col0 = (tid & 31) * 4;
    int row0 = (tid >> 5) * 4;
    float acc[4][4];
#pragma unroll
    for (int r = 0; r < 4; ++r)
#pragma unroll
        for (int c = 0; c < 4; ++c) acc[r][c] = 0.f;

    for (int k = 0; k < 128; ++k) {
        float4 w = *(const float4*)&Wl[k * 128 + col0];
#pragma unroll
        for (int r = 0; r < 4; ++r) {
            float a = As[row0 + r][k];
            acc[r][0] += a * w.x; acc[r][1] += a * w.y;
            acc[r][2] += a * w.z; acc[r][3] += a * w.w;
        }
    }
    for (int k = 0; k < 128; ++k) {
        float4 w = *(const float4*)&Wr[k * 128 + col0];
#pragma unroll
        for (int r = 0; r < 4; ++r) {
            float a = As[row0 + r][k + 128];
            acc[r][0] += a * w.x; acc[r][1] += a * w.y;
            acc[r][2] += a * w.z; acc[r][3] += a * w.w;
        }
    }

    float4 b = *(const float4*)&bias[col0];
#pragma unroll
    for (int r = 0; r < 4; ++r) {
        int n = n0 + row0 + r;
        if (n < n_nodes) {
            float4 o;
            o.x = fmaxf(acc[r][0] + b.x, 0.f);
            o.y = fmaxf(acc[r][1] + b.y, 0.f);
            o.z = fmaxf(acc[r][2] + b.z, 0.f);
            o.w = fmaxf(acc[r][3] + b.w, 0.f);
            *(float4*)&out[(size_t)n * 128 + col0] = o;
        }
    }
}

// ---------------- layer 2 reordered: project first, then aggregate ----------------
// Wp[128][128]: cols 0..46 = Wl2, cols 64..110 = Wr2, rest zero.
__global__ void pad_w_kernel(const float* __restrict__ Wl, const float* __restrict__ Wr,
                             float* __restrict__ Wp) {
    int idx = blockIdx.x * blockDim.x + threadIdx.x;
    if (idx >= 128 * 128) return;
    int k = idx >> 7;
    int c = idx & 127;
    float v = 0.f;
    if (c < 47) v = Wl[k * 47 + c];
    else if (c >= 64 && c < 111) v = Wr[k * 47 + (c - 64)];
    Wp[idx] = v;
}

// G = H @ Wp  (100k x 128, K=128). Same structure as gemm128, single K-loop.
__global__ __launch_bounds__(256) void gemm_G_kernel(const float* __restrict__ h,
                                                     const float* __restrict__ Wp,
                                                     float* __restrict__ G, int n_nodes) {
    __shared__ float As[32][128];
    int tid = threadIdx.x;
    int n0 = blockIdx.x * 32;
    for (int idx = tid; idx < 1024; idx += 256) {
        int row = idx >> 5;
        int k4 = idx & 31;
        int n = n0 + row;
        float4 v = make_float4(0.f, 0.f, 0.f, 0.f);
        if (n < n_nodes) v = ((const float4*)h)[(size_t)n * 32 + k4];
        *(float4*)&As[row][k4 * 4] = v;
    }
    __syncthreads();

    int col0 = (tid & 31) * 4;
    int row0 = (tid >> 5) * 4;
    float acc[4][4];
#pragma unroll
    for (int r = 0; r < 4; ++r)
#pragma unroll
        for (int c = 0; c < 4; ++c) acc[r][c] = 0.f;

    for (int k = 0; k < 128; ++k) {
        float4 w = *(const float4*)&Wp[k * 128 + col0];
#pragma unroll
        for (int r = 0; r < 4; ++r) {
            float a = As[row0 + r][k];
            acc[r][0] += a * w.x; acc[r][1] += a * w.y;
            acc[r][2] += a * w.z; acc[r][3] += a * w.w;
        }
    }

#pragma unroll
    for (int r = 0; r < 4; ++r) {
        int n = n0 + row0 + r;
        if (n < n_nodes)
            *(float4*)&G[(size_t)n * 128 + col0] =
                make_float4(acc[r][0], acc[r][1], acc[r][2], acc[r][3]);
    }
}

// Epilogue: out[n] = log_softmax( invdeg[n]*sum_{s in N(n)} G[s][0:47]
//                                 + G[n][64:111] + b )
// One 64-lane wave per node; lane c owns column c (47 real, rest -inf pad).
__global__ __launch_bounds__(256) void out_kernel(const float* __restrict__ G,
                                                  const int* __restrict__ rowptr,
                                                  const int* __restrict__ ssrc,
                                                  const float* __restrict__ inv_deg,
                                                  const float* __restrict__ bias,
                                                  float* __restrict__ out, int n_nodes) {
    int lane = threadIdx.x & 63;
    int n = blockIdx.x * 4 + (threadIdx.x >> 6);
    if (n >= n_nodes) return;
    bool ok = lane < 47;
    int col = ok ? lane : 46;  // clamp: inactive lanes re-read last useful word (same line)
    int e0 = rowptr[n], e1 = rowptr[n + 1];
    float acc = 0.f;
    int e = e0;
    for (; e + 1 < e1; e += 2) {
        int s0 = ssrc[e];
        int s1 = ssrc[e + 1];
        float g0 = G[(size_t)s0 * 128 + col];
        float g1 = G[(size_t)s1 * 128 + col];
        acc += g0 + g1;
    }
    if (e < e1) acc += G[(size_t)ssrc[e] * 128 + col];

    float v = -INFINITY;
    if (ok) v = acc * inv_deg[n] + G[(size_t)n * 128 + 64 + col] + bias[col];

    float m = v;
#pragma unroll
    for (int off = 32; off >= 1; off >>= 1)
        m = fmaxf(m, __shfl_xor(m, off, 64));
    float s = ok ? __expf(v - m) : 0.f;
#pragma unroll
    for (int off = 32; off >= 1; off >>= 1)
        s += __shfl_xor(s, off, 64);
    float ls = __logf(s);
    if (ok) out[(size_t)n * 47 + lane] = v - m - ls;
}

// ---------------- launch ----------------

extern "C" void kernel_launch(void* const* d_in, const int* in_sizes, int n_in,
                              void* d_out, int out_size, void* d_ws, size_t ws_size,
                              hipStream_t stream) {
    const float* x   = (const float*)d_in[0];
    const int*   src = (const int*)d_in[1];
    const int*   dst = (const int*)d_in[2];
    const float* Wl0 = (const float*)d_in[3];
    const float* bl0 = (const float*)d_in[4];
    const float* Wr0 = (const float*)d_in[5];
    const float* Wl1 = (const float*)d_in[6];
    const float* bl1 = (const float*)d_in[7];
    const float* Wr1 = (const float*)d_in[8];
    const float* Wl2 = (const float*)d_in[9];
    const float* bl2 = (const float*)d_in[10];
    const float* Wr2 = (const float*)d_in[11];
    float* out = (float*)d_out;

    int N = in_sizes[0] / 128;
    int E = in_sizes[1];

    char* ws = (char*)d_ws;
    size_t off = 0;
    auto alloc = [&](size_t bytes) -> char* {
        char* p = ws + off;
        off += (bytes + 255) & ~(size_t)255;
        return p;
    };
    int*   cnt    = (int*)alloc((size_t)N * 4);
    int*   rowptr = (int*)alloc((size_t)(N + 1) * 4);
    int*   cursor = (int*)alloc((size_t)N * 4);
    float* invd   = (float*)alloc((size_t)N * 4);
    int*   ssrc   = (int*)alloc((size_t)E * 4);
    float* aggb   = (float*)alloc((size_t)N * 128 * 4);  // also reused as G for layer 2
    float* hbuf   = (float*)alloc((size_t)N * 128 * 4);
    float* Wp     = (float*)alloc(128 * 128 * 4);

    hipMemsetAsync(cnt, 0, (size_t)N * 4, stream);
    hist_kernel<<<(E + 255) / 256, 256, 0, stream>>>(dst, cnt, E);
    scan_kernel<<<1, 1024, 0, stream>>>(cnt, rowptr, N);
    invdeg_copy_kernel<<<(N + 255) / 256, 256, 0, stream>>>(cnt, rowptr, invd, cursor, N);
    scatter_kernel<<<(E + 255) / 256, 256, 0, stream>>>(src, dst, cursor, ssrc, E);
    pad_w_kernel<<<64, 256, 0, stream>>>(Wl2, Wr2, Wp);

    int aggGrid  = (N + 7) / 8;
    int gemmGrid = (N + 31) / 32;

    // layer 0: x -> hbuf
    agg_kernel<<<aggGrid, 256, 0, stream>>>((const float4*)x, rowptr, ssrc, invd,
                                            (float4*)aggb, N);
    gemm128_kernel<<<gemmGrid, 256, 0, stream>>>(aggb, x, Wl0, Wr0, bl0, hbuf, N);

    // layer 1: hbuf -> hbuf (in-place safe: rows staged in LDS before stores)
    agg_kernel<<<aggGrid, 256, 0, stream>>>((const float4*)hbuf, rowptr, ssrc, invd,
                                            (float4*)aggb, N);
    gemm128_kernel<<<gemmGrid, 256, 0, stream>>>(aggb, hbuf, Wl1, Wr1, bl1, hbuf, N);

    // layer 2 (reordered): G = hbuf @ [Wl2|Wr2], then 47-wide aggregate + log_softmax
    float* G = aggb;
    gemm_G_kernel<<<gemmGrid, 256, 0, stream>>>(hbuf, Wp, G, N);
    out_kernel<<<(N + 3) / 4, 256, 0, stream>>>(G, rowptr, ssrc, invd, bl2, out, N);
}

// Round 3
// 940.661 us; speedup vs baseline: 1.3535x; 1.1593x over previous
//
#include <hip/hip_runtime.h>
#include <math.h>

// ---------------- CSR build ----------------

__global__ void hist_kernel(const int* __restrict__ dst, int* __restrict__ cnt, int n_edges) {
    int e = blockIdx.x * blockDim.x + threadIdx.x;
    if (e < n_edges) atomicAdd(&cnt[dst[e]], 1);
}

// Phase A: per-block (2048-elem) sums.
__global__ __launch_bounds__(256) void block_sum_kernel(const int* __restrict__ cnt,
                                                        int* __restrict__ bsum, int n) {
    int tid = threadIdx.x;
    int i0 = blockIdx.x * 2048 + tid * 8;
    int s = 0;
#pragma unroll
    for (int j = 0; j < 8; ++j) {
        int i = i0 + j;
        if (i < n) s += cnt[i];
    }
#pragma unroll
    for (int off = 32; off >= 1; off >>= 1) s += __shfl_xor(s, off, 64);
    __shared__ int ws[4];
    if ((tid & 63) == 0) ws[tid >> 6] = s;
    __syncthreads();
    if (tid == 0) bsum[blockIdx.x] = ws[0] + ws[1] + ws[2] + ws[3];
}

// Phase B: exclusive scan of the ~49 block sums (serial on one thread; tiny).
__global__ void scan_bsum_kernel(int* __restrict__ bsum, int nb) {
    if (blockIdx.x == 0 && threadIdx.x == 0) {
        int run = 0;
        for (int i = 0; i < nb; ++i) {
            int v = bsum[i];
            bsum[i] = run;
            run += v;
        }
    }
}

// Phase C: local scan + block offset -> rowptr, cursor, inv_deg in one pass.
__global__ __launch_bounds__(256) void scan_write_kernel(const int* __restrict__ cnt,
                                                         const int* __restrict__ bsum,
                                                         int* __restrict__ rowptr,
                                                         int* __restrict__ cursor,
                                                         float* __restrict__ invd, int n) {
    int tid = threadIdx.x;
    int i0 = blockIdx.x * 2048 + tid * 8;
    int vals[8];
    int s = 0;
#pragma unroll
    for (int j = 0; j < 8; ++j) {
        int i = i0 + j;
        vals[j] = (i < n) ? cnt[i] : 0;
        s += vals[j];
    }
    int lane = tid & 63, wave = tid >> 6;
    int v = s;
#pragma unroll
    for (int off = 1; off < 64; off <<= 1) {
        int t = __shfl_up(v, off, 64);
        if (lane >= off) v += t;
    }
    __shared__ int wsum[4], woff[4];
    if (lane == 63) wsum[wave] = v;
    __syncthreads();
    if (tid == 0) {
        int run = 0;
#pragma unroll
        for (int w = 0; w < 4; ++w) { woff[w] = run; run += wsum[w]; }
    }
    __syncthreads();
    int run = bsum[blockIdx.x] + woff[wave] + (v - s);  // exclusive prefix for elem i0
#pragma unroll
    for (int j = 0; j < 8; ++j) {
        int i = i0 + j;
        if (i < n) {
            int c = vals[j];
            cursor[i] = run;
            invd[i] = c > 0 ? 1.0f / (float)c : 0.0f;
            rowptr[i + 1] = run + c;
            run += c;
        }
    }
    if (blockIdx.x == 0 && tid == 0) rowptr[0] = 0;
}

__global__ void scatter_kernel(const int* __restrict__ src, const int* __restrict__ dst,
                               int* __restrict__ cursor, int* __restrict__ ssrc, int n_edges) {
    int e = blockIdx.x * blockDim.x + threadIdx.x;
    if (e < n_edges) {
        int p = atomicAdd(&cursor[dst[e]], 1);
        ssrc[p] = src[e];
    }
}

// ---------------- mean aggregation (gather over CSR), layers 0/1 ----------------
__global__ __launch_bounds__(256) void agg_kernel(const float4* __restrict__ h4,
                                                  const int* __restrict__ rowptr,
                                                  const int* __restrict__ ssrc,
                                                  const float* __restrict__ inv_deg,
                                                  float4* __restrict__ agg4, int n_nodes) {
    int tid = threadIdx.x;
    int d = tid & 31;
    int n = blockIdx.x * 8 + (tid >> 5);
    if (n >= n_nodes) return;
    int e0 = rowptr[n], e1 = rowptr[n + 1];
    float4 acc = make_float4(0.f, 0.f, 0.f, 0.f);
    int e = e0;
    for (; e + 1 < e1; e += 2) {
        int s0 = ssrc[e];
        int s1 = ssrc[e + 1];
        float4 v0 = h4[(size_t)s0 * 32 + d];
        float4 v1 = h4[(size_t)s1 * 32 + d];
        acc.x += v0.x; acc.y += v0.y; acc.z += v0.z; acc.w += v0.w;
        acc.x += v1.x; acc.y += v1.y; acc.z += v1.z; acc.w += v1.w;
    }
    if (e < e1) {
        int s = ssrc[e];
        float4 vv = h4[(size_t)s * 32 + d];
        acc.x += vv.x; acc.y += vv.y; acc.z += vv.z; acc.w += vv.w;
    }
    float w = inv_deg[n];
    acc.x *= w; acc.y *= w; acc.z *= w; acc.w *= w;
    agg4[(size_t)n * 32 + d] = acc;
}

// ---------------- fused GEMM: out = relu([agg|h] @ [Wl;Wr] + b), dout=128 ----------------
__global__ __launch_bounds__(256) void gemm128_kernel(const float* __restrict__ agg,
                                                      const float* __restrict__ h,
                                                      const float* __restrict__ Wl,
                                                      const float* __restrict__ Wr,
                                                      const float* __restrict__ bias,
                                                      float* __restrict__ out, int n_nodes) {
    __shared__ float As[32][256];
    int tid = threadIdx.x;
    int n0 = blockIdx.x * 32;
    for (int idx = tid; idx < 2048; idx += 256) {
        int row = idx >> 6;
        int k4 = idx & 63;
        int n = n0 + row;
        float4 v = make_float4(0.f, 0.f, 0.f, 0.f);
        if (n < n_nodes) {
            v = (k4 < 32) ? ((const float4*)agg)[(size_t)n * 32 + k4]
                          : ((const float4*)h)[(size_t)n * 32 + (k4 - 32)];
        }
        *(float4*)&As[row][k4 * 4] = v;
    }
    __syncthreads();

    int col0 = (tid & 31) * 4;
    int row0 = (tid >> 5) * 4;
    float acc[4][4];
#pragma unroll
    for (int r = 0; r < 4; ++r)
#pragma unroll
        for (int c = 0; c < 4; ++c) acc[r][c] = 0.f;

    for (int k = 0; k < 128; ++k) {
        float4 w = *(const float4*)&Wl[k * 128 + col0];
#pragma unroll
        for (int r = 0; r < 4; ++r) {
            float a = As[row0 + r][k];
            acc[r][0] += a * w.x; acc[r][1] += a * w.y;
            acc[r][2] += a * w.z; acc[r][3] += a * w.w;
        }
    }
    for (int k = 0; k < 128; ++k) {
        float4 w = *(const float4*)&Wr[k * 128 + col0];
#pragma unroll
        for (int r = 0; r < 4; ++r) {
            float a = As[row0 + r][k + 128];
            acc[r][0] += a * w.x; acc[r][1] += a * w.y;
            acc[r][2] += a * w.z; acc[r][3] += a * w.w;
        }
    }

    float4 b = *(const float4*)&bias[col0];
#pragma unroll
    for (int r = 0; r < 4; ++r) {
        int n = n0 + row0 + r;
        if (n < n_nodes) {
            float4 o;
            o.x = fmaxf(acc[r][0] + b.x, 0.f);
            o.y = fmaxf(acc[r][1] + b.y, 0.f);
            o.z = fmaxf(acc[r][2] + b.z, 0.f);
            o.w = fmaxf(acc[r][3] + b.w, 0.f);
            *(float4*)&out[(size_t)n * 128 + col0] = o;
        }
    }
}

// ---------------- layer 2 reordered: project first, then aggregate ----------------
__global__ void pad_w_kernel(const float* __restrict__ Wl, const float* __restrict__ Wr,
                             float* __restrict__ Wp) {
    int idx = blockIdx.x * blockDim.x + threadIdx.x;
    if (idx >= 128 * 128) return;
    int k = idx >> 7;
    int c = idx & 127;
    float v = 0.f;
    if (c < 47) v = Wl[k * 47 + c];
    else if (c >= 64 && c < 111) v = Wr[k * 47 + (c - 64)];
    Wp[idx] = v;
}

__global__ __launch_bounds__(256) void gemm_G_kernel(const float* __restrict__ h,
                                                     const float* __restrict__ Wp,
                                                     float* __restrict__ G, int n_nodes) {
    __shared__ float As[32][128];
    int tid = threadIdx.x;
    int n0 = blockIdx.x * 32;
    for (int idx = tid; idx < 1024; idx += 256) {
        int row = idx >> 5;
        int k4 = idx & 31;
        int n = n0 + row;
        float4 v = make_float4(0.f, 0.f, 0.f, 0.f);
        if (n < n_nodes) v = ((const float4*)h)[(size_t)n * 32 + k4];
        *(float4*)&As[row][k4 * 4] = v;
    }
    __syncthreads();

    int col0 = (tid & 31) * 4;
    int row0 = (tid >> 5) * 4;
    float acc[4][4];
#pragma unroll
    for (int r = 0; r < 4; ++r)
#pragma unroll
        for (int c = 0; c < 4; ++c) acc[r][c] = 0.f;

    for (int k = 0; k < 128; ++k) {
        float4 w = *(const float4*)&Wp[k * 128 + col0];
#pragma unroll
        for (int r = 0; r < 4; ++r) {
            float a = As[row0 + r][k];
            acc[r][0] += a * w.x; acc[r][1] += a * w.y;
            acc[r][2] += a * w.z; acc[r][3] += a * w.w;
        }
    }

#pragma unroll
    for (int r = 0; r < 4; ++r) {
        int n = n0 + row0 + r;
        if (n < n_nodes)
            *(float4*)&G[(size_t)n * 128 + col0] =
                make_float4(acc[r][0], acc[r][1], acc[r][2], acc[r][3]);
    }
}

// Epilogue: out[n] = log_softmax( invdeg[n]*sum_{s in N(n)} G[s][0:47]
//                                 + G[n][64:111] + b )
__global__ __launch_bounds__(256) void out_kernel(const float* __restrict__ G,
                                                  const int* __restrict__ rowptr,
                                                  const int* __restrict__ ssrc,
                                                  const float* __restrict__ inv_deg,
                                                  const float* __restrict__ bias,
                                                  float* __restrict__ out, int n_nodes) {
    int lane = threadIdx.x & 63;
    int n = blockIdx.x * 4 + (threadIdx.x >> 6);
    if (n >= n_nodes) return;
    bool ok = lane < 47;
    int col = ok ? lane : 46;
    int e0 = rowptr[n], e1 = rowptr[n + 1];
    float acc = 0.f;
    int e = e0;
    for (; e + 1 < e1; e += 2) {
        int s0 = ssrc[e];
        int s1 = ssrc[e + 1];
        float g0 = G[(size_t)s0 * 128 + col];
        float g1 = G[(size_t)s1 * 128 + col];
        acc += g0 + g1;
    }
    if (e < e1) acc += G[(size_t)ssrc[e] * 128 + col];

    float v = -INFINITY;
    if (ok) v = acc * inv_deg[n] + G[(size_t)n * 128 + 64 + col] + bias[col];

    float m = v;
#pragma unroll
    for (int off = 32; off >= 1; off >>= 1)
        m = fmaxf(m, __shfl_xor(m, off, 64));
    float s = ok ? __expf(v - m) : 0.f;
#pragma unroll
    for (int off = 32; off >= 1; off >>= 1)
        s += __shfl_xor(s, off, 64);
    float ls = __logf(s);
    if (ok) out[(size_t)n * 47 + lane] = v - m - ls;
}

// ---------------- launch ----------------

extern "C" void kernel_launch(void* const* d_in, const int* in_sizes, int n_in,
                              void* d_out, int out_size, void* d_ws, size_t ws_size,
                              hipStream_t stream) {
    const float* x   = (const float*)d_in[0];
    const int*   src = (const int*)d_in[1];
    const int*   dst = (const int*)d_in[2];
    const float* Wl0 = (const float*)d_in[3];
    const float* bl0 = (const float*)d_in[4];
    const float* Wr0 = (const float*)d_in[5];
    const float* Wl1 = (const float*)d_in[6];
    const float* bl1 = (const float*)d_in[7];
    const float* Wr1 = (const float*)d_in[8];
    const float* Wl2 = (const float*)d_in[9];
    const float* bl2 = (const float*)d_in[10];
    const float* Wr2 = (const float*)d_in[11];
    float* out = (float*)d_out;

    int N = in_sizes[0] / 128;
    int E = in_sizes[1];

    char* ws = (char*)d_ws;
    size_t off = 0;
    auto alloc = [&](size_t bytes) -> char* {
        char* p = ws + off;
        off += (bytes + 255) & ~(size_t)255;
        return p;
    };
    int*   cnt    = (int*)alloc((size_t)N * 4);
    int*   rowptr = (int*)alloc((size_t)(N + 1) * 4);
    int*   cursor = (int*)alloc((size_t)N * 4);
    float* invd   = (float*)alloc((size_t)N * 4);
    int*   ssrc   = (int*)alloc((size_t)E * 4);
    float* aggb   = (float*)alloc((size_t)N * 128 * 4);  // reused as G for layer 2
    float* hbuf   = (float*)alloc((size_t)N * 128 * 4);
    float* Wp     = (float*)alloc(128 * 128 * 4);
    int*   bsum   = (int*)alloc(256 * 4);

    int nScanBlocks = (N + 2047) / 2048;

    hipMemsetAsync(cnt, 0, (size_t)N * 4, stream);
    hist_kernel<<<(E + 255) / 256, 256, 0, stream>>>(dst, cnt, E);
    block_sum_kernel<<<nScanBlocks, 256, 0, stream>>>(cnt, bsum, N);
    scan_bsum_kernel<<<1, 64, 0, stream>>>(bsum, nScanBlocks);
    scan_write_kernel<<<nScanBlocks, 256, 0, stream>>>(cnt, bsum, rowptr, cursor, invd, N);
    scatter_kernel<<<(E + 255) / 256, 256, 0, stream>>>(src, dst, cursor, ssrc, E);
    pad_w_kernel<<<64, 256, 0, stream>>>(Wl2, Wr2, Wp);

    int aggGrid  = (N + 7) / 8;
    int gemmGrid = (N + 31) / 32;

    // layer 0: x -> hbuf
    agg_kernel<<<aggGrid, 256, 0, stream>>>((const float4*)x, rowptr, ssrc, invd,
                                            (float4*)aggb, N);
    gemm128_kernel<<<gemmGrid, 256, 0, stream>>>(aggb, x, Wl0, Wr0, bl0, hbuf, N);

    // layer 1: hbuf -> hbuf (in-place safe: rows staged in LDS before stores)
    agg_kernel<<<aggGrid, 256, 0, stream>>>((const float4*)hbuf, rowptr, ssrc, invd,
                                            (float4*)aggb, N);
    gemm128_kernel<<<gemmGrid, 256, 0, stream>>>(aggb, hbuf, Wl1, Wr1, bl1, hbuf, N);

    // layer 2 (reordered): G = hbuf @ [Wl2|Wr2], then 47-wide aggregate + log_softmax
    float* G = aggb;
    gemm_G_kernel<<<gemmGrid, 256, 0, stream>>>(hbuf, Wp, G, N);
    out_kernel<<<(N + 3) / 4, 256, 0, stream>>>(G, rowptr, ssrc, invd, bl2, out, N);
}

// Round 4
// 892.933 us; speedup vs baseline: 1.4259x; 1.0535x over previous
//
#include <hip/hip_runtime.h>
#include <math.h>

// ---------------- CSR build ----------------

__global__ void hist_kernel(const int* __restrict__ dst, int* __restrict__ cnt, int n_edges) {
    int e = blockIdx.x * blockDim.x + threadIdx.x;
    if (e < n_edges) atomicAdd(&cnt[dst[e]], 1);
}

// Phase A: per-block (2048-elem) sums.
__global__ __launch_bounds__(256) void block_sum_kernel(const int* __restrict__ cnt,
                                                        int* __restrict__ bsum, int n) {
    int tid = threadIdx.x;
    int i0 = blockIdx.x * 2048 + tid * 8;
    int s = 0;
#pragma unroll
    for (int j = 0; j < 8; ++j) {
        int i = i0 + j;
        if (i < n) s += cnt[i];
    }
#pragma unroll
    for (int off = 32; off >= 1; off >>= 1) s += __shfl_xor(s, off, 64);
    __shared__ int ws[4];
    if ((tid & 63) == 0) ws[tid >> 6] = s;
    __syncthreads();
    if (tid == 0) bsum[blockIdx.x] = ws[0] + ws[1] + ws[2] + ws[3];
}

// Phase B: exclusive scan of the ~49 block sums (serial on one thread; tiny).
__global__ void scan_bsum_kernel(int* __restrict__ bsum, int nb) {
    if (blockIdx.x == 0 && threadIdx.x == 0) {
        int run = 0;
        for (int i = 0; i < nb; ++i) {
            int v = bsum[i];
            bsum[i] = run;
            run += v;
        }
    }
}

// Phase C: local scan + block offset -> rowptr, cursor, inv_deg in one pass.
__global__ __launch_bounds__(256) void scan_write_kernel(const int* __restrict__ cnt,
                                                         const int* __restrict__ bsum,
                                                         int* __restrict__ rowptr,
                                                         int* __restrict__ cursor,
                                                         float* __restrict__ invd, int n) {
    int tid = threadIdx.x;
    int i0 = blockIdx.x * 2048 + tid * 8;
    int vals[8];
    int s = 0;
#pragma unroll
    for (int j = 0; j < 8; ++j) {
        int i = i0 + j;
        vals[j] = (i < n) ? cnt[i] : 0;
        s += vals[j];
    }
    int lane = tid & 63, wave = tid >> 6;
    int v = s;
#pragma unroll
    for (int off = 1; off < 64; off <<= 1) {
        int t = __shfl_up(v, off, 64);
        if (lane >= off) v += t;
    }
    __shared__ int wsum[4], woff[4];
    if (lane == 63) wsum[wave] = v;
    __syncthreads();
    if (tid == 0) {
        int run = 0;
#pragma unroll
        for (int w = 0; w < 4; ++w) { woff[w] = run; run += wsum[w]; }
    }
    __syncthreads();
    int run = bsum[blockIdx.x] + woff[wave] + (v - s);
#pragma unroll
    for (int j = 0; j < 8; ++j) {
        int i = i0 + j;
        if (i < n) {
            int c = vals[j];
            cursor[i] = run;
            invd[i] = c > 0 ? 1.0f / (float)c : 0.0f;
            rowptr[i + 1] = run + c;
            run += c;
        }
    }
    if (blockIdx.x == 0 && tid == 0) rowptr[0] = 0;
}

__global__ void scatter_kernel(const int* __restrict__ src, const int* __restrict__ dst,
                               int* __restrict__ cursor, int* __restrict__ ssrc, int n_edges) {
    int e = blockIdx.x * blockDim.x + threadIdx.x;
    if (e < n_edges) {
        int p = atomicAdd(&cursor[dst[e]], 1);
        ssrc[p] = src[e];
    }
}

// ---------------- mean aggregation (gather over CSR), layers 0/1 ----------------
// Edge loop unrolled x4 for memory-level parallelism (ssrc->gather is a chained load).
__global__ __launch_bounds__(256) void agg_kernel(const float4* __restrict__ h4,
                                                  const int* __restrict__ rowptr,
                                                  const int* __restrict__ ssrc,
                                                  const float* __restrict__ inv_deg,
                                                  float4* __restrict__ agg4, int n_nodes) {
    int tid = threadIdx.x;
    int d = tid & 31;
    int n = blockIdx.x * 8 + (tid >> 5);
    if (n >= n_nodes) return;
    int e0 = rowptr[n], e1 = rowptr[n + 1];
    float4 acc = make_float4(0.f, 0.f, 0.f, 0.f);
    int e = e0;
    for (; e + 3 < e1; e += 4) {
        int s0 = ssrc[e], s1 = ssrc[e + 1], s2 = ssrc[e + 2], s3 = ssrc[e + 3];
        float4 v0 = h4[(size_t)s0 * 32 + d];
        float4 v1 = h4[(size_t)s1 * 32 + d];
        float4 v2 = h4[(size_t)s2 * 32 + d];
        float4 v3 = h4[(size_t)s3 * 32 + d];
        acc.x += v0.x + v1.x + v2.x + v3.x;
        acc.y += v0.y + v1.y + v2.y + v3.y;
        acc.z += v0.z + v1.z + v2.z + v3.z;
        acc.w += v0.w + v1.w + v2.w + v3.w;
    }
    for (; e < e1; ++e) {
        int s = ssrc[e];
        float4 vv = h4[(size_t)s * 32 + d];
        acc.x += vv.x; acc.y += vv.y; acc.z += vv.z; acc.w += vv.w;
    }
    float w = inv_deg[n];
    acc.x *= w; acc.y *= w; acc.z *= w; acc.w *= w;
    agg4[(size_t)n * 32 + d] = acc;
}

// ---------------- fused GEMM: out = relu([agg|h] @ [Wl;Wr] + b), dout=128 ----------------
// k-loop unrolled x4; A rows read as ds_read_b128 (wave-uniform -> broadcast).
__global__ __launch_bounds__(256) void gemm128_kernel(const float* __restrict__ agg,
                                                      const float* __restrict__ h,
                                                      const float* __restrict__ Wl,
                                                      const float* __restrict__ Wr,
                                                      const float* __restrict__ bias,
                                                      float* __restrict__ out, int n_nodes) {
    __shared__ float As[32][256];
    int tid = threadIdx.x;
    int n0 = blockIdx.x * 32;
    for (int idx = tid; idx < 2048; idx += 256) {
        int row = idx >> 6;
        int k4 = idx & 63;
        int n = n0 + row;
        float4 v = make_float4(0.f, 0.f, 0.f, 0.f);
        if (n < n_nodes) {
            v = (k4 < 32) ? ((const float4*)agg)[(size_t)n * 32 + k4]
                          : ((const float4*)h)[(size_t)n * 32 + (k4 - 32)];
        }
        *(float4*)&As[row][k4 * 4] = v;
    }
    __syncthreads();

    int col0 = (tid & 31) * 4;
    int row0 = (tid >> 5) * 4;
    float acc[4][4];
#pragma unroll
    for (int r = 0; r < 4; ++r)
#pragma unroll
        for (int c = 0; c < 4; ++c) acc[r][c] = 0.f;

#pragma unroll 2
    for (int k = 0; k < 128; k += 4) {
        float4 w0 = *(const float4*)&Wl[(k + 0) * 128 + col0];
        float4 w1 = *(const float4*)&Wl[(k + 1) * 128 + col0];
        float4 w2 = *(const float4*)&Wl[(k + 2) * 128 + col0];
        float4 w3 = *(const float4*)&Wl[(k + 3) * 128 + col0];
        float4 a[4];
#pragma unroll
        for (int r = 0; r < 4; ++r) a[r] = *(const float4*)&As[row0 + r][k];
#pragma unroll
        for (int r = 0; r < 4; ++r) {
            acc[r][0] += a[r].x * w0.x; acc[r][1] += a[r].x * w0.y;
            acc[r][2] += a[r].x * w0.z; acc[r][3] += a[r].x * w0.w;
            acc[r][0] += a[r].y * w1.x; acc[r][1] += a[r].y * w1.y;
            acc[r][2] += a[r].y * w1.z; acc[r][3] += a[r].y * w1.w;
            acc[r][0] += a[r].z * w2.x; acc[r][1] += a[r].z * w2.y;
            acc[r][2] += a[r].z * w2.z; acc[r][3] += a[r].z * w2.w;
            acc[r][0] += a[r].w * w3.x; acc[r][1] += a[r].w * w3.y;
            acc[r][2] += a[r].w * w3.z; acc[r][3] += a[r].w * w3.w;
        }
    }
#pragma unroll 2
    for (int k = 0; k < 128; k += 4) {
        float4 w0 = *(const float4*)&Wr[(k + 0) * 128 + col0];
        float4 w1 = *(const float4*)&Wr[(k + 1) * 128 + col0];
        float4 w2 = *(const float4*)&Wr[(k + 2) * 128 + col0];
        float4 w3 = *(const float4*)&Wr[(k + 3) * 128 + col0];
        float4 a[4];
#pragma unroll
        for (int r = 0; r < 4; ++r) a[r] = *(const float4*)&As[row0 + r][k + 128];
#pragma unroll
        for (int r = 0; r < 4; ++r) {
            acc[r][0] += a[r].x * w0.x; acc[r][1] += a[r].x * w0.y;
            acc[r][2] += a[r].x * w0.z; acc[r][3] += a[r].x * w0.w;
            acc[r][0] += a[r].y * w1.x; acc[r][1] += a[r].y * w1.y;
            acc[r][2] += a[r].y * w1.z; acc[r][3] += a[r].y * w1.w;
            acc[r][0] += a[r].z * w2.x; acc[r][1] += a[r].z * w2.y;
            acc[r][2] += a[r].z * w2.z; acc[r][3] += a[r].z * w2.w;
            acc[r][0] += a[r].w * w3.x; acc[r][1] += a[r].w * w3.y;
            acc[r][2] += a[r].w * w3.z; acc[r][3] += a[r].w * w3.w;
        }
    }

    float4 b = *(const float4*)&bias[col0];
#pragma unroll
    for (int r = 0; r < 4; ++r) {
        int n = n0 + row0 + r;
        if (n < n_nodes) {
            float4 o;
            o.x = fmaxf(acc[r][0] + b.x, 0.f);
            o.y = fmaxf(acc[r][1] + b.y, 0.f);
            o.z = fmaxf(acc[r][2] + b.z, 0.f);
            o.w = fmaxf(acc[r][3] + b.w, 0.f);
            *(float4*)&out[(size_t)n * 128 + col0] = o;
        }
    }
}

// ---------------- layer 2 reordered: project first, then aggregate ----------------
__global__ void pad_w_kernel(const float* __restrict__ Wl, const float* __restrict__ Wr,
                             float* __restrict__ Wp) {
    int idx = blockIdx.x * blockDim.x + threadIdx.x;
    if (idx >= 128 * 128) return;
    int k = idx >> 7;
    int c = idx & 127;
    float v = 0.f;
    if (c < 47) v = Wl[k * 47 + c];
    else if (c >= 64 && c < 111) v = Wr[k * 47 + (c - 64)];
    Wp[idx] = v;
}

__global__ __launch_bounds__(256) void gemm_G_kernel(const float* __restrict__ h,
                                                     const float* __restrict__ Wp,
                                                     float* __restrict__ G, int n_nodes) {
    __shared__ float As[32][128];
    int tid = threadIdx.x;
    int n0 = blockIdx.x * 32;
    for (int idx = tid; idx < 1024; idx += 256) {
        int row = idx >> 5;
        int k4 = idx & 31;
        int n = n0 + row;
        float4 v = make_float4(0.f, 0.f, 0.f, 0.f);
        if (n < n_nodes) v = ((const float4*)h)[(size_t)n * 32 + k4];
        *(float4*)&As[row][k4 * 4] = v;
    }
    __syncthreads();

    int col0 = (tid & 31) * 4;
    int row0 = (tid >> 5) * 4;
    float acc[4][4];
#pragma unroll
    for (int r = 0; r < 4; ++r)
#pragma unroll
        for (int c = 0; c < 4; ++c) acc[r][c] = 0.f;

#pragma unroll 2
    for (int k = 0; k < 128; k += 4) {
        float4 w0 = *(const float4*)&Wp[(k + 0) * 128 + col0];
        float4 w1 = *(const float4*)&Wp[(k + 1) * 128 + col0];
        float4 w2 = *(const float4*)&Wp[(k + 2) * 128 + col0];
        float4 w3 = *(const float4*)&Wp[(k + 3) * 128 + col0];
        float4 a[4];
#pragma unroll
        for (int r = 0; r < 4; ++r) a[r] = *(const float4*)&As[row0 + r][k];
#pragma unroll
        for (int r = 0; r < 4; ++r) {
            acc[r][0] += a[r].x * w0.x; acc[r][1] += a[r].x * w0.y;
            acc[r][2] += a[r].x * w0.z; acc[r][3] += a[r].x * w0.w;
            acc[r][0] += a[r].y * w1.x; acc[r][1] += a[r].y * w1.y;
            acc[r][2] += a[r].y * w1.z; acc[r][3] += a[r].y * w1.w;
            acc[r][0] += a[r].z * w2.x; acc[r][1] += a[r].z * w2.y;
            acc[r][2] += a[r].z * w2.z; acc[r][3] += a[r].z * w2.w;
            acc[r][0] += a[r].w * w3.x; acc[r][1] += a[r].w * w3.y;
            acc[r][2] += a[r].w * w3.z; acc[r][3] += a[r].w * w3.w;
        }
    }

#pragma unroll
    for (int r = 0; r < 4; ++r) {
        int n = n0 + row0 + r;
        if (n < n_nodes)
            *(float4*)&G[(size_t)n * 128 + col0] =
                make_float4(acc[r][0], acc[r][1], acc[r][2], acc[r][3]);
    }
}

// Epilogue: out[n] = log_softmax( invdeg[n]*sum_{s in N(n)} G[s][0:47]
//                                 + G[n][64:111] + b )
__global__ __launch_bounds__(256) void out_kernel(const float* __restrict__ G,
                                                  const int* __restrict__ rowptr,
                                                  const int* __restrict__ ssrc,
                                                  const float* __restrict__ inv_deg,
                                                  const float* __restrict__ bias,
                                                  float* __restrict__ out, int n_nodes) {
    int lane = threadIdx.x & 63;
    int n = blockIdx.x * 4 + (threadIdx.x >> 6);
    if (n >= n_nodes) return;
    bool ok = lane < 47;
    int col = ok ? lane : 46;
    int e0 = rowptr[n], e1 = rowptr[n + 1];
    float acc = 0.f;
    int e = e0;
    for (; e + 3 < e1; e += 4) {
        int s0 = ssrc[e], s1 = ssrc[e + 1], s2 = ssrc[e + 2], s3 = ssrc[e + 3];
        float g0 = G[(size_t)s0 * 128 + col];
        float g1 = G[(size_t)s1 * 128 + col];
        float g2 = G[(size_t)s2 * 128 + col];
        float g3 = G[(size_t)s3 * 128 + col];
        acc += g0 + g1 + g2 + g3;
    }
    for (; e < e1; ++e) acc += G[(size_t)ssrc[e] * 128 + col];

    float v = -INFINITY;
    if (ok) v = acc * inv_deg[n] + G[(size_t)n * 128 + 64 + col] + bias[col];

    float m = v;
#pragma unroll
    for (int off = 32; off >= 1; off >>= 1)
        m = fmaxf(m, __shfl_xor(m, off, 64));
    float s = ok ? __expf(v - m) : 0.f;
#pragma unroll
    for (int off = 32; off >= 1; off >>= 1)
        s += __shfl_xor(s, off, 64);
    float ls = __logf(s);
    if (ok) out[(size_t)n * 47 + lane] = v - m - ls;
}

// ---------------- launch ----------------

extern "C" void kernel_launch(void* const* d_in, const int* in_sizes, int n_in,
                              void* d_out, int out_size, void* d_ws, size_t ws_size,
                              hipStream_t stream) {
    const float* x   = (const float*)d_in[0];
    const int*   src = (const int*)d_in[1];
    const int*   dst = (const int*)d_in[2];
    const float* Wl0 = (const float*)d_in[3];
    const float* bl0 = (const float*)d_in[4];
    const float* Wr0 = (const float*)d_in[5];
    const float* Wl1 = (const float*)d_in[6];
    const float* bl1 = (const float*)d_in[7];
    const float* Wr1 = (const float*)d_in[8];
    const float* Wl2 = (const float*)d_in[9];
    const float* bl2 = (const float*)d_in[10];
    const float* Wr2 = (const float*)d_in[11];
    float* out = (float*)d_out;

    int N = in_sizes[0] / 128;
    int E = in_sizes[1];

    char* ws = (char*)d_ws;
    size_t off = 0;
    auto alloc = [&](size_t bytes) -> char* {
        char* p = ws + off;
        off += (bytes + 255) & ~(size_t)255;
        return p;
    };
    int*   cnt    = (int*)alloc((size_t)N * 4);
    int*   rowptr = (int*)alloc((size_t)(N + 1) * 4);
    int*   cursor = (int*)alloc((size_t)N * 4);
    float* invd   = (float*)alloc((size_t)N * 4);
    int*   ssrc   = (int*)alloc((size_t)E * 4);
    float* aggb   = (float*)alloc((size_t)N * 128 * 4);  // reused as G for layer 2
    float* hbuf   = (float*)alloc((size_t)N * 128 * 4);
    float* Wp     = (float*)alloc(128 * 128 * 4);
    int*   bsum   = (int*)alloc(256 * 4);

    int nScanBlocks = (N + 2047) / 2048;

    hipMemsetAsync(cnt, 0, (size_t)N * 4, stream);
    hist_kernel<<<(E + 255) / 256, 256, 0, stream>>>(dst, cnt, E);
    block_sum_kernel<<<nScanBlocks, 256, 0, stream>>>(cnt, bsum, N);
    scan_bsum_kernel<<<1, 64, 0, stream>>>(bsum, nScanBlocks);
    scan_write_kernel<<<nScanBlocks, 256, 0, stream>>>(cnt, bsum, rowptr, cursor, invd, N);
    scatter_kernel<<<(E + 255) / 256, 256, 0, stream>>>(src, dst, cursor, ssrc, E);
    pad_w_kernel<<<64, 256, 0, stream>>>(Wl2, Wr2, Wp);

    int aggGrid  = (N + 7) / 8;
    int gemmGrid = (N + 31) / 32;

    // layer 0: x -> hbuf
    agg_kernel<<<aggGrid, 256, 0, stream>>>((const float4*)x, rowptr, ssrc, invd,
                                            (float4*)aggb, N);
    gemm128_kernel<<<gemmGrid, 256, 0, stream>>>(aggb, x, Wl0, Wr0, bl0, hbuf, N);

    // layer 1: hbuf -> hbuf (in-place safe: rows staged in LDS before stores)
    agg_kernel<<<aggGrid, 256, 0, stream>>>((const float4*)hbuf, rowptr, ssrc, invd,
                                            (float4*)aggb, N);
    gemm128_kernel<<<gemmGrid, 256, 0, stream>>>(aggb, hbuf, Wl1, Wr1, bl1, hbuf, N);

    // layer 2 (reordered): G = hbuf @ [Wl2|Wr2], then 47-wide aggregate + log_softmax
    float* G = aggb;
    gemm_G_kernel<<<gemmGrid, 256, 0, stream>>>(hbuf, Wp, G, N);
    out_kernel<<<(N + 3) / 4, 256, 0, stream>>>(G, rowptr, ssrc, invd, bl2, out, N);
}

// Round 5
// 823.046 us; speedup vs baseline: 1.5469x; 1.0849x over previous
//
#include <hip/hip_runtime.h>
#include <math.h>

#define BUCKET_SHIFT 8  // 256 nodes per bucket

// ---------------- CSR build ----------------

__global__ void hist_kernel(const int* __restrict__ dst, int* __restrict__ cnt, int n_edges) {
    int e = blockIdx.x * blockDim.x + threadIdx.x;
    if (e < n_edges) atomicAdd(&cnt[dst[e]], 1);
}

// Phase A: per-block (2048-elem) sums.
__global__ __launch_bounds__(256) void block_sum_kernel(const int* __restrict__ cnt,
                                                        int* __restrict__ bsum, int n) {
    int tid = threadIdx.x;
    int i0 = blockIdx.x * 2048 + tid * 8;
    int s = 0;
#pragma unroll
    for (int j = 0; j < 8; ++j) {
        int i = i0 + j;
        if (i < n) s += cnt[i];
    }
#pragma unroll
    for (int off = 32; off >= 1; off >>= 1) s += __shfl_xor(s, off, 64);
    __shared__ int ws[4];
    if ((tid & 63) == 0) ws[tid >> 6] = s;
    __syncthreads();
    if (tid == 0) bsum[blockIdx.x] = ws[0] + ws[1] + ws[2] + ws[3];
}

// Phase B: exclusive scan of the ~49 block sums (serial on one thread; tiny).
__global__ void scan_bsum_kernel(int* __restrict__ bsum, int nb) {
    if (blockIdx.x == 0 && threadIdx.x == 0) {
        int run = 0;
        for (int i = 0; i < nb; ++i) {
            int v = bsum[i];
            bsum[i] = run;
            run += v;
        }
    }
}

// Phase C: local scan + block offset -> rowptr, inv_deg in one pass.
__global__ __launch_bounds__(256) void scan_write_kernel(const int* __restrict__ cnt,
                                                         const int* __restrict__ bsum,
                                                         int* __restrict__ rowptr,
                                                         float* __restrict__ invd, int n) {
    int tid = threadIdx.x;
    int i0 = blockIdx.x * 2048 + tid * 8;
    int vals[8];
    int s = 0;
#pragma unroll
    for (int j = 0; j < 8; ++j) {
        int i = i0 + j;
        vals[j] = (i < n) ? cnt[i] : 0;
        s += vals[j];
    }
    int lane = tid & 63, wave = tid >> 6;
    int v = s;
#pragma unroll
    for (int off = 1; off < 64; off <<= 1) {
        int t = __shfl_up(v, off, 64);
        if (lane >= off) v += t;
    }
    __shared__ int wsum[4], woff[4];
    if (lane == 63) wsum[wave] = v;
    __syncthreads();
    if (tid == 0) {
        int run = 0;
#pragma unroll
        for (int w = 0; w < 4; ++w) { woff[w] = run; run += wsum[w]; }
    }
    __syncthreads();
    int run = bsum[blockIdx.x] + woff[wave] + (v - s);
#pragma unroll
    for (int j = 0; j < 8; ++j) {
        int i = i0 + j;
        if (i < n) {
            int c = vals[j];
            invd[i] = c > 0 ? 1.0f / (float)c : 0.0f;
            rowptr[i + 1] = run + c;
            run += c;
        }
    }
    if (blockIdx.x == 0 && tid == 0) rowptr[0] = 0;
}

__global__ void init_gcursor_kernel(const int* __restrict__ rowptr, int* __restrict__ gcursor,
                                    int nbuckets) {
    int j = blockIdx.x * blockDim.x + threadIdx.x;
    if (j < nbuckets) gcursor[j] = rowptr[j << BUCKET_SHIFT];
}

// Pass B: chunk-per-block; per-bucket contiguous reservations so each block's
// intermediate writes form single-XCD runs (kills cross-XCD partial-line writebacks).
__global__ __launch_bounds__(256) void bucket_scatter_kernel(const int* __restrict__ src,
                                                             const int* __restrict__ dst,
                                                             int* __restrict__ gcursor,
                                                             int2* __restrict__ interm,
                                                             int n_edges, int nbuckets) {
    __shared__ int hist[512];
    __shared__ int gbase[512];
    int tid = threadIdx.x;
    for (int j = tid; j < nbuckets; j += 256) hist[j] = 0;
    __syncthreads();
    int e0 = blockIdx.x * 16384;
    int e1 = min(e0 + 16384, n_edges);
    for (int e = e0 + tid; e < e1; e += 256)
        atomicAdd(&hist[dst[e] >> BUCKET_SHIFT], 1);
    __syncthreads();
    for (int j = tid; j < nbuckets; j += 256) {
        int c = hist[j];
        gbase[j] = c > 0 ? atomicAdd(&gcursor[j], c) : 0;
        hist[j] = 0;  // reuse as local cursor
    }
    __syncthreads();
    for (int e = e0 + tid; e < e1; e += 256) {
        int d = dst[e];
        int s = src[e];
        int j = d >> BUCKET_SHIFT;
        int p = atomicAdd(&hist[j], 1);
        interm[gbase[j] + p] = make_int2(d, s);
    }
}

// Pass C: one block per bucket; scatter src into the bucket's CONTIGUOUS ssrc
// region (single block -> single XCD -> full-line L2 coverage before writeback).
__global__ __launch_bounds__(256) void bucket_sort_kernel(const int2* __restrict__ interm,
                                                          const int* __restrict__ rowptr,
                                                          int* __restrict__ ssrc, int n_nodes) {
    __shared__ int cur[256];
    int tid = threadIdx.x;
    int nb0 = blockIdx.x << BUCKET_SHIFT;
    int nEnd = min(nb0 + 256, n_nodes);
    int base = rowptr[nb0];
    int end = rowptr[nEnd];
    if (nb0 + tid < n_nodes) cur[tid] = rowptr[nb0 + tid] - base;
    __syncthreads();
    for (int e = base + tid; e < end; e += 256) {
        int2 p = interm[e];
        int pos = atomicAdd(&cur[p.x - nb0], 1);
        ssrc[base + pos] = p.y;
    }
}

// ---------------- mean aggregation (gather over CSR), layers 0/1 ----------------
__global__ __launch_bounds__(256) void agg_kernel(const float4* __restrict__ h4,
                                                  const int* __restrict__ rowptr,
                                                  const int* __restrict__ ssrc,
                                                  const float* __restrict__ inv_deg,
                                                  float4* __restrict__ agg4, int n_nodes) {
    int tid = threadIdx.x;
    int d = tid & 31;
    int n = blockIdx.x * 8 + (tid >> 5);
    if (n >= n_nodes) return;
    int e0 = rowptr[n], e1 = rowptr[n + 1];
    float4 acc = make_float4(0.f, 0.f, 0.f, 0.f);
    int e = e0;
    for (; e + 3 < e1; e += 4) {
        int s0 = ssrc[e], s1 = ssrc[e + 1], s2 = ssrc[e + 2], s3 = ssrc[e + 3];
        float4 v0 = h4[(size_t)s0 * 32 + d];
        float4 v1 = h4[(size_t)s1 * 32 + d];
        float4 v2 = h4[(size_t)s2 * 32 + d];
        float4 v3 = h4[(size_t)s3 * 32 + d];
        acc.x += v0.x + v1.x + v2.x + v3.x;
        acc.y += v0.y + v1.y + v2.y + v3.y;
        acc.z += v0.z + v1.z + v2.z + v3.z;
        acc.w += v0.w + v1.w + v2.w + v3.w;
    }
    for (; e < e1; ++e) {
        int s = ssrc[e];
        float4 vv = h4[(size_t)s * 32 + d];
        acc.x += vv.x; acc.y += vv.y; acc.z += vv.z; acc.w += vv.w;
    }
    float w = inv_deg[n];
    acc.x *= w; acc.y *= w; acc.z *= w; acc.w *= w;
    agg4[(size_t)n * 32 + d] = acc;
}

// ---------------- fused GEMM: out = relu([agg|h] @ [Wl;Wr] + b), dout=128 ----------------
__global__ __launch_bounds__(256) void gemm128_kernel(const float* __restrict__ agg,
                                                      const float* __restrict__ h,
                                                      const float* __restrict__ Wl,
                                                      const float* __restrict__ Wr,
                                                      const float* __restrict__ bias,
                                                      float* __restrict__ out, int n_nodes) {
    __shared__ float As[32][256];
    int tid = threadIdx.x;
    int n0 = blockIdx.x * 32;
    for (int idx = tid; idx < 2048; idx += 256) {
        int row = idx >> 6;
        int k4 = idx & 63;
        int n = n0 + row;
        float4 v = make_float4(0.f, 0.f, 0.f, 0.f);
        if (n < n_nodes) {
            v = (k4 < 32) ? ((const float4*)agg)[(size_t)n * 32 + k4]
                          : ((const float4*)h)[(size_t)n * 32 + (k4 - 32)];
        }
        *(float4*)&As[row][k4 * 4] = v;
    }
    __syncthreads();

    int col0 = (tid & 31) * 4;
    int row0 = (tid >> 5) * 4;
    float acc[4][4];
#pragma unroll
    for (int r = 0; r < 4; ++r)
#pragma unroll
        for (int c = 0; c < 4; ++c) acc[r][c] = 0.f;

#pragma unroll 2
    for (int k = 0; k < 128; k += 4) {
        float4 w0 = *(const float4*)&Wl[(k + 0) * 128 + col0];
        float4 w1 = *(const float4*)&Wl[(k + 1) * 128 + col0];
        float4 w2 = *(const float4*)&Wl[(k + 2) * 128 + col0];
        float4 w3 = *(const float4*)&Wl[(k + 3) * 128 + col0];
        float4 a[4];
#pragma unroll
        for (int r = 0; r < 4; ++r) a[r] = *(const float4*)&As[row0 + r][k];
#pragma unroll
        for (int r = 0; r < 4; ++r) {
            acc[r][0] += a[r].x * w0.x; acc[r][1] += a[r].x * w0.y;
            acc[r][2] += a[r].x * w0.z; acc[r][3] += a[r].x * w0.w;
            acc[r][0] += a[r].y * w1.x; acc[r][1] += a[r].y * w1.y;
            acc[r][2] += a[r].y * w1.z; acc[r][3] += a[r].y * w1.w;
            acc[r][0] += a[r].z * w2.x; acc[r][1] += a[r].z * w2.y;
            acc[r][2] += a[r].z * w2.z; acc[r][3] += a[r].z * w2.w;
            acc[r][0] += a[r].w * w3.x; acc[r][1] += a[r].w * w3.y;
            acc[r][2] += a[r].w * w3.z; acc[r][3] += a[r].w * w3.w;
        }
    }
#pragma unroll 2
    for (int k = 0; k < 128; k += 4) {
        float4 w0 = *(const float4*)&Wr[(k + 0) * 128 + col0];
        float4 w1 = *(const float4*)&Wr[(k + 1) * 128 + col0];
        float4 w2 = *(const float4*)&Wr[(k + 2) * 128 + col0];
        float4 w3 = *(const float4*)&Wr[(k + 3) * 128 + col0];
        float4 a[4];
#pragma unroll
        for (int r = 0; r < 4; ++r) a[r] = *(const float4*)&As[row0 + r][k + 128];
#pragma unroll
        for (int r = 0; r < 4; ++r) {
            acc[r][0] += a[r].x * w0.x; acc[r][1] += a[r].x * w0.y;
            acc[r][2] += a[r].x * w0.z; acc[r][3] += a[r].x * w0.w;
            acc[r][0] += a[r].y * w1.x; acc[r][1] += a[r].y * w1.y;
            acc[r][2] += a[r].y * w1.z; acc[r][3] += a[r].y * w1.w;
            acc[r][0] += a[r].z * w2.x; acc[r][1] += a[r].z * w2.y;
            acc[r][2] += a[r].z * w2.z; acc[r][3] += a[r].z * w2.w;
            acc[r][0] += a[r].w * w3.x; acc[r][1] += a[r].w * w3.y;
            acc[r][2] += a[r].w * w3.z; acc[r][3] += a[r].w * w3.w;
        }
    }

    float4 b = *(const float4*)&bias[col0];
#pragma unroll
    for (int r = 0; r < 4; ++r) {
        int n = n0 + row0 + r;
        if (n < n_nodes) {
            float4 o;
            o.x = fmaxf(acc[r][0] + b.x, 0.f);
            o.y = fmaxf(acc[r][1] + b.y, 0.f);
            o.z = fmaxf(acc[r][2] + b.z, 0.f);
            o.w = fmaxf(acc[r][3] + b.w, 0.f);
            *(float4*)&out[(size_t)n * 128 + col0] = o;
        }
    }
}

// ---------------- layer 2 reordered: project first, then aggregate ----------------
__global__ void pad_w_kernel(const float* __restrict__ Wl, const float* __restrict__ Wr,
                             float* __restrict__ Wp) {
    int idx = blockIdx.x * blockDim.x + threadIdx.x;
    if (idx >= 128 * 128) return;
    int k = idx >> 7;
    int c = idx & 127;
    float v = 0.f;
    if (c < 47) v = Wl[k * 47 + c];
    else if (c >= 64 && c < 111) v = Wr[k * 47 + (c - 64)];
    Wp[idx] = v;
}

__global__ __launch_bounds__(256) void gemm_G_kernel(const float* __restrict__ h,
                                                     const float* __restrict__ Wp,
                                                     float* __restrict__ G, int n_nodes) {
    __shared__ float As[32][128];
    int tid = threadIdx.x;
    int n0 = blockIdx.x * 32;
    for (int idx = tid; idx < 1024; idx += 256) {
        int row = idx >> 5;
        int k4 = idx & 31;
        int n = n0 + row;
        float4 v = make_float4(0.f, 0.f, 0.f, 0.f);
        if (n < n_nodes) v = ((const float4*)h)[(size_t)n * 32 + k4];
        *(float4*)&As[row][k4 * 4] = v;
    }
    __syncthreads();

    int col0 = (tid & 31) * 4;
    int row0 = (tid >> 5) * 4;
    float acc[4][4];
#pragma unroll
    for (int r = 0; r < 4; ++r)
#pragma unroll
        for (int c = 0; c < 4; ++c) acc[r][c] = 0.f;

#pragma unroll 2
    for (int k = 0; k < 128; k += 4) {
        float4 w0 = *(const float4*)&Wp[(k + 0) * 128 + col0];
        float4 w1 = *(const float4*)&Wp[(k + 1) * 128 + col0];
        float4 w2 = *(const float4*)&Wp[(k + 2) * 128 + col0];
        float4 w3 = *(const float4*)&Wp[(k + 3) * 128 + col0];
        float4 a[4];
#pragma unroll
        for (int r = 0; r < 4; ++r) a[r] = *(const float4*)&As[row0 + r][k];
#pragma unroll
        for (int r = 0; r < 4; ++r) {
            acc[r][0] += a[r].x * w0.x; acc[r][1] += a[r].x * w0.y;
            acc[r][2] += a[r].x * w0.z; acc[r][3] += a[r].x * w0.w;
            acc[r][0] += a[r].y * w1.x; acc[r][1] += a[r].y * w1.y;
            acc[r][2] += a[r].y * w1.z; acc[r][3] += a[r].y * w1.w;
            acc[r][0] += a[r].z * w2.x; acc[r][1] += a[r].z * w2.y;
            acc[r][2] += a[r].z * w2.z; acc[r][3] += a[r].z * w2.w;
            acc[r][0] += a[r].w * w3.x; acc[r][1] += a[r].w * w3.y;
            acc[r][2] += a[r].w * w3.z; acc[r][3] += a[r].w * w3.w;
        }
    }

#pragma unroll
    for (int r = 0; r < 4; ++r) {
        int n = n0 + row0 + r;
        if (n < n_nodes)
            *(float4*)&G[(size_t)n * 128 + col0] =
                make_float4(acc[r][0], acc[r][1], acc[r][2], acc[r][3]);
    }
}

// Epilogue: out[n] = log_softmax( invdeg[n]*sum_{s in N(n)} G[s][0:47]
//                                 + G[n][64:111] + b )
__global__ __launch_bounds__(256) void out_kernel(const float* __restrict__ G,
                                                  const int* __restrict__ rowptr,
                                                  const int* __restrict__ ssrc,
                                                  const float* __restrict__ inv_deg,
                                                  const float* __restrict__ bias,
                                                  float* __restrict__ out, int n_nodes) {
    int lane = threadIdx.x & 63;
    int n = blockIdx.x * 4 + (threadIdx.x >> 6);
    if (n >= n_nodes) return;
    bool ok = lane < 47;
    int col = ok ? lane : 46;
    int e0 = rowptr[n], e1 = rowptr[n + 1];
    float acc = 0.f;
    int e = e0;
    for (; e + 3 < e1; e += 4) {
        int s0 = ssrc[e], s1 = ssrc[e + 1], s2 = ssrc[e + 2], s3 = ssrc[e + 3];
        float g0 = G[(size_t)s0 * 128 + col];
        float g1 = G[(size_t)s1 * 128 + col];
        float g2 = G[(size_t)s2 * 128 + col];
        float g3 = G[(size_t)s3 * 128 + col];
        acc += g0 + g1 + g2 + g3;
    }
    for (; e < e1; ++e) acc += G[(size_t)ssrc[e] * 128 + col];

    float v = -INFINITY;
    if (ok) v = acc * inv_deg[n] + G[(size_t)n * 128 + 64 + col] + bias[col];

    float m = v;
#pragma unroll
    for (int off = 32; off >= 1; off >>= 1)
        m = fmaxf(m, __shfl_xor(m, off, 64));
    float s = ok ? __expf(v - m) : 0.f;
#pragma unroll
    for (int off = 32; off >= 1; off >>= 1)
        s += __shfl_xor(s, off, 64);
    float ls = __logf(s);
    if (ok) out[(size_t)n * 47 + lane] = v - m - ls;
}

// ---------------- launch ----------------

extern "C" void kernel_launch(void* const* d_in, const int* in_sizes, int n_in,
                              void* d_out, int out_size, void* d_ws, size_t ws_size,
                              hipStream_t stream) {
    const float* x   = (const float*)d_in[0];
    const int*   src = (const int*)d_in[1];
    const int*   dst = (const int*)d_in[2];
    const float* Wl0 = (const float*)d_in[3];
    const float* bl0 = (const float*)d_in[4];
    const float* Wr0 = (const float*)d_in[5];
    const float* Wl1 = (const float*)d_in[6];
    const float* bl1 = (const float*)d_in[7];
    const float* Wr1 = (const float*)d_in[8];
    const float* Wl2 = (const float*)d_in[9];
    const float* bl2 = (const float*)d_in[10];
    const float* Wr2 = (const float*)d_in[11];
    float* out = (float*)d_out;

    int N = in_sizes[0] / 128;
    int E = in_sizes[1];
    int nBuckets = (N + 255) >> BUCKET_SHIFT;

    char* ws = (char*)d_ws;
    size_t off = 0;
    auto alloc = [&](size_t bytes) -> char* {
        char* p = ws + off;
        off += (bytes + 255) & ~(size_t)255;
        return p;
    };
    int*   cnt    = (int*)alloc((size_t)N * 4);
    int*   rowptr = (int*)alloc((size_t)(N + 1) * 4);
    float* invd   = (float*)alloc((size_t)N * 4);
    int*   ssrc   = (int*)alloc((size_t)E * 4);
    float* aggb   = (float*)alloc((size_t)N * 128 * 4);  // reused: interm (CSR) then G (layer 2)
    float* hbuf   = (float*)alloc((size_t)N * 128 * 4);
    float* Wp     = (float*)alloc(128 * 128 * 4);
    int*   bsum   = (int*)alloc(256 * 4);
    int*   gcur   = (int*)alloc(512 * 4);

    int2* interm = (int2*)aggb;  // 12.8 MB <= 51.2 MB, used only before agg writes aggb

    int nScanBlocks = (N + 2047) / 2048;

    hipMemsetAsync(cnt, 0, (size_t)N * 4, stream);
    hist_kernel<<<(E + 255) / 256, 256, 0, stream>>>(dst, cnt, E);
    block_sum_kernel<<<nScanBlocks, 256, 0, stream>>>(cnt, bsum, N);
    scan_bsum_kernel<<<1, 64, 0, stream>>>(bsum, nScanBlocks);
    scan_write_kernel<<<nScanBlocks, 256, 0, stream>>>(cnt, bsum, rowptr, invd, N);
    init_gcursor_kernel<<<(nBuckets + 255) / 256, 256, 0, stream>>>(rowptr, gcur, nBuckets);
    bucket_scatter_kernel<<<(E + 16383) / 16384, 256, 0, stream>>>(src, dst, gcur, interm,
                                                                   E, nBuckets);
    bucket_sort_kernel<<<nBuckets, 256, 0, stream>>>(interm, rowptr, ssrc, N);
    pad_w_kernel<<<64, 256, 0, stream>>>(Wl2, Wr2, Wp);

    int aggGrid  = (N + 7) / 8;
    int gemmGrid = (N + 31) / 32;

    // layer 0: x -> hbuf
    agg_kernel<<<aggGrid, 256, 0, stream>>>((const float4*)x, rowptr, ssrc, invd,
                                            (float4*)aggb, N);
    gemm128_kernel<<<gemmGrid, 256, 0, stream>>>(aggb, x, Wl0, Wr0, bl0, hbuf, N);

    // layer 1: hbuf -> hbuf (in-place safe: rows staged in LDS before stores)
    agg_kernel<<<aggGrid, 256, 0, stream>>>((const float4*)hbuf, rowptr, ssrc, invd,
                                            (float4*)aggb, N);
    gemm128_kernel<<<gemmGrid, 256, 0, stream>>>(aggb, hbuf, Wl1, Wr1, bl1, hbuf, N);

    // layer 2 (reordered): G = hbuf @ [Wl2|Wr2], then 47-wide aggregate + log_softmax
    float* G = aggb;
    gemm_G_kernel<<<gemmGrid, 256, 0, stream>>>(hbuf, Wp, G, N);
    out_kernel<<<(N + 3) / 4, 256, 0, stream>>>(G, rowptr, ssrc, invd, bl2, out, N);
}

// Round 6
// 634.969 us; speedup vs baseline: 2.0051x; 1.2962x over previous
//
#include <hip/hip_runtime.h>
#include <math.h>

#define BUCKET_SHIFT 8  // 256 nodes per bucket

typedef short s8v __attribute__((ext_vector_type(8)));   // 8 bf16 (4 VGPRs)
typedef float f4v __attribute__((ext_vector_type(4)));   // 4 fp32 acc

__device__ inline unsigned short f2bf(float f) {  // RNE fp32->bf16
    unsigned u = __float_as_uint(f);
    return (unsigned short)((u + 0x7FFFu + ((u >> 16) & 1u)) >> 16);
}

// ---------------- CSR build ----------------

__global__ void hist_kernel(const int* __restrict__ dst, int* __restrict__ cnt, int n_edges) {
    int e = blockIdx.x * blockDim.x + threadIdx.x;
    if (e < n_edges) atomicAdd(&cnt[dst[e]], 1);
}

__global__ __launch_bounds__(256) void block_sum_kernel(const int* __restrict__ cnt,
                                                        int* __restrict__ bsum, int n) {
    int tid = threadIdx.x;
    int i0 = blockIdx.x * 2048 + tid * 8;
    int s = 0;
#pragma unroll
    for (int j = 0; j < 8; ++j) {
        int i = i0 + j;
        if (i < n) s += cnt[i];
    }
#pragma unroll
    for (int off = 32; off >= 1; off >>= 1) s += __shfl_xor(s, off, 64);
    __shared__ int ws[4];
    if ((tid & 63) == 0) ws[tid >> 6] = s;
    __syncthreads();
    if (tid == 0) bsum[blockIdx.x] = ws[0] + ws[1] + ws[2] + ws[3];
}

__global__ void scan_bsum_kernel(int* __restrict__ bsum, int nb) {
    if (blockIdx.x == 0 && threadIdx.x == 0) {
        int run = 0;
        for (int i = 0; i < nb; ++i) {
            int v = bsum[i];
            bsum[i] = run;
            run += v;
        }
    }
}

__global__ __launch_bounds__(256) void scan_write_kernel(const int* __restrict__ cnt,
                                                         const int* __restrict__ bsum,
                                                         int* __restrict__ rowptr,
                                                         float* __restrict__ invd, int n) {
    int tid = threadIdx.x;
    int i0 = blockIdx.x * 2048 + tid * 8;
    int vals[8];
    int s = 0;
#pragma unroll
    for (int j = 0; j < 8; ++j) {
        int i = i0 + j;
        vals[j] = (i < n) ? cnt[i] : 0;
        s += vals[j];
    }
    int lane = tid & 63, wave = tid >> 6;
    int v = s;
#pragma unroll
    for (int off = 1; off < 64; off <<= 1) {
        int t = __shfl_up(v, off, 64);
        if (lane >= off) v += t;
    }
    __shared__ int wsum[4], woff[4];
    if (lane == 63) wsum[wave] = v;
    __syncthreads();
    if (tid == 0) {
        int run = 0;
#pragma unroll
        for (int w = 0; w < 4; ++w) { woff[w] = run; run += wsum[w]; }
    }
    __syncthreads();
    int run = bsum[blockIdx.x] + woff[wave] + (v - s);
#pragma unroll
    for (int j = 0; j < 8; ++j) {
        int i = i0 + j;
        if (i < n) {
            int c = vals[j];
            invd[i] = c > 0 ? 1.0f / (float)c : 0.0f;
            rowptr[i + 1] = run + c;
            run += c;
        }
    }
    if (blockIdx.x == 0 && tid == 0) rowptr[0] = 0;
}

__global__ void init_gcursor_kernel(const int* __restrict__ rowptr, int* __restrict__ gcursor,
                                    int nbuckets) {
    int j = blockIdx.x * blockDim.x + threadIdx.x;
    if (j < nbuckets) gcursor[j] = rowptr[j << BUCKET_SHIFT];
}

__global__ __launch_bounds__(256) void bucket_scatter_kernel(const int* __restrict__ src,
                                                             const int* __restrict__ dst,
                                                             int* __restrict__ gcursor,
                                                             int2* __restrict__ interm,
                                                             int n_edges, int nbuckets) {
    __shared__ int hist[512];
    __shared__ int gbase[512];
    int tid = threadIdx.x;
    for (int j = tid; j < nbuckets; j += 256) hist[j] = 0;
    __syncthreads();
    int e0 = blockIdx.x * 16384;
    int e1 = min(e0 + 16384, n_edges);
    for (int e = e0 + tid; e < e1; e += 256)
        atomicAdd(&hist[dst[e] >> BUCKET_SHIFT], 1);
    __syncthreads();
    for (int j = tid; j < nbuckets; j += 256) {
        int c = hist[j];
        gbase[j] = c > 0 ? atomicAdd(&gcursor[j], c) : 0;
        hist[j] = 0;
    }
    __syncthreads();
    for (int e = e0 + tid; e < e1; e += 256) {
        int d = dst[e];
        int s = src[e];
        int j = d >> BUCKET_SHIFT;
        int p = atomicAdd(&hist[j], 1);
        interm[gbase[j] + p] = make_int2(d, s);
    }
}

__global__ __launch_bounds__(256) void bucket_sort_kernel(const int2* __restrict__ interm,
                                                          const int* __restrict__ rowptr,
                                                          int* __restrict__ ssrc, int n_nodes) {
    __shared__ int cur[256];
    int tid = threadIdx.x;
    int nb0 = blockIdx.x << BUCKET_SHIFT;
    int nEnd = min(nb0 + 256, n_nodes);
    int base = rowptr[nb0];
    int end = rowptr[nEnd];
    if (nb0 + tid < n_nodes) cur[tid] = rowptr[nb0 + tid] - base;
    __syncthreads();
    for (int e = base + tid; e < end; e += 256) {
        int2 p = interm[e];
        int pos = atomicAdd(&cur[p.x - nb0], 1);
        ssrc[base + pos] = p.y;
    }
}

// ---------------- weight packing into MFMA fragment order ----------------
// frag index for W[k][c] (K x 128): kt=k>>5, q=(k>>3)&3, j=k&7, ct=c>>4, n=c&15
//   -> out[(((kt*8+ct)*64 + q*16 + n)<<3) + j]
__global__ void pack01_kernel(const float* __restrict__ Wl, const float* __restrict__ Wr,
                              unsigned short* __restrict__ out) {
    int idx = blockIdx.x * 256 + threadIdx.x;  // 256*128
    if (idx >= 32768) return;
    int k = idx >> 7, c = idx & 127;
    float v = (k < 128) ? Wl[k * 128 + c] : Wr[(k - 128) * 128 + c];
    int kt = k >> 5, q = (k >> 3) & 3, j = k & 7, ct = c >> 4, n = c & 15;
    out[(((kt * 8 + ct) * 64 + q * 16 + n) << 3) + j] = f2bf(v);
}

// layer-2 W padded: cols 0..46 = Wl2, 64..110 = Wr2, rest 0 (K=128)
__global__ void packl2_kernel(const float* __restrict__ Wl, const float* __restrict__ Wr,
                              unsigned short* __restrict__ out) {
    int idx = blockIdx.x * 256 + threadIdx.x;  // 128*128
    if (idx >= 16384) return;
    int k = idx >> 7, c = idx & 127;
    float v = 0.f;
    if (c < 47) v = Wl[k * 47 + c];
    else if (c >= 64 && c < 111) v = Wr[k * 47 + (c - 64)];
    int kt = k >> 5, q = (k >> 3) & 3, j = k & 7, ct = c >> 4, n = c & 15;
    out[(((kt * 8 + ct) * 64 + q * 16 + n) << 3) + j] = f2bf(v);
}

// ---------------- mean aggregation (gather over CSR), layers 0/1 ----------------
__global__ __launch_bounds__(256) void agg_kernel(const float4* __restrict__ h4,
                                                  const int* __restrict__ rowptr,
                                                  const int* __restrict__ ssrc,
                                                  const float* __restrict__ inv_deg,
                                                  float4* __restrict__ agg4, int n_nodes) {
    int tid = threadIdx.x;
    int d = tid & 31;
    int n = blockIdx.x * 8 + (tid >> 5);
    if (n >= n_nodes) return;
    int e0 = rowptr[n], e1 = rowptr[n + 1];
    float4 acc = make_float4(0.f, 0.f, 0.f, 0.f);
    int e = e0;
    for (; e + 3 < e1; e += 4) {
        int s0 = ssrc[e], s1 = ssrc[e + 1], s2 = ssrc[e + 2], s3 = ssrc[e + 3];
        float4 v0 = h4[(size_t)s0 * 32 + d];
        float4 v1 = h4[(size_t)s1 * 32 + d];
        float4 v2 = h4[(size_t)s2 * 32 + d];
        float4 v3 = h4[(size_t)s3 * 32 + d];
        acc.x += v0.x + v1.x + v2.x + v3.x;
        acc.y += v0.y + v1.y + v2.y + v3.y;
        acc.z += v0.z + v1.z + v2.z + v3.z;
        acc.w += v0.w + v1.w + v2.w + v3.w;
    }
    for (; e < e1; ++e) {
        int s = ssrc[e];
        float4 vv = h4[(size_t)s * 32 + d];
        acc.x += vv.x; acc.y += vv.y; acc.z += vv.z; acc.w += vv.w;
    }
    float w = inv_deg[n];
    acc.x *= w; acc.y *= w; acc.z *= w; acc.w *= w;
    agg4[(size_t)n * 32 + d] = acc;
}

// ---------------- MFMA GEMM: out = relu([agg|h] @ Wfrag + b), K=256, N=128 ----------------
// 32 rows/block; 4 waves: rt = wave&1 (16-row tile), ch = wave>>1 (64-col half).
// A staged fp32->bf16 in LDS (stride 264: a-frag ds_read_b128 is bank-balanced).
__global__ __launch_bounds__(256) void gemm128_mfma(const float* __restrict__ agg,
                                                    const float* __restrict__ h,
                                                    const unsigned short* __restrict__ Wfrag,
                                                    const float* __restrict__ bias,
                                                    float* __restrict__ out, int n_nodes) {
    __shared__ unsigned short As[32][264];
    int tid = threadIdx.x;
    int n0 = blockIdx.x * 32;
    for (int i = tid; i < 1024; i += 256) {  // 32 rows x 32 chunks of 8
        int row = i >> 5, c8 = i & 31;
        int n = n0 + row;
        union { unsigned short u[8]; s8v v; } t;
        if (n < n_nodes) {
            const float* p = (c8 < 16) ? &agg[(size_t)n * 128 + c8 * 8]
                                       : &h[(size_t)n * 128 + (c8 - 16) * 8];
            float4 lo = *(const float4*)p;
            float4 hi = *(const float4*)(p + 4);
            t.u[0] = f2bf(lo.x); t.u[1] = f2bf(lo.y); t.u[2] = f2bf(lo.z); t.u[3] = f2bf(lo.w);
            t.u[4] = f2bf(hi.x); t.u[5] = f2bf(hi.y); t.u[6] = f2bf(hi.z); t.u[7] = f2bf(hi.w);
        } else {
#pragma unroll
            for (int j = 0; j < 8; ++j) t.u[j] = 0;
        }
        *(s8v*)&As[row][c8 * 8] = t.v;
    }
    __syncthreads();

    int wave = tid >> 6, lane = tid & 63;
    int rt = wave & 1, ch = wave >> 1;
    int m = lane & 15, q = lane >> 4;

    f4v acc[4];
#pragma unroll
    for (int c = 0; c < 4; ++c) acc[c] = (f4v){0.f, 0.f, 0.f, 0.f};

#pragma unroll
    for (int kt = 0; kt < 8; ++kt) {
        s8v a = *(const s8v*)&As[rt * 16 + m][kt * 32 + q * 8];
#pragma unroll
        for (int c = 0; c < 4; ++c) {
            int ctg = ch * 4 + c;
            s8v b = *(const s8v*)&Wfrag[(((size_t)kt * 8 + ctg) * 64 + lane) * 8];
            acc[c] = __builtin_amdgcn_mfma_f32_16x16x32_bf16(a, b, acc[c], 0, 0, 0);
        }
    }

#pragma unroll
    for (int c = 0; c < 4; ++c) {
        int col = ch * 64 + c * 16 + m;
        float bc = bias[col];
#pragma unroll
        for (int r = 0; r < 4; ++r) {
            int n = n0 + rt * 16 + q * 4 + r;
            if (n < n_nodes)
                out[(size_t)n * 128 + col] = fmaxf(acc[c][r] + bc, 0.f);
        }
    }
}

// ---------------- MFMA GEMM: G = h @ Wfrag2, K=128, N=128 (no bias/relu) ----------------
__global__ __launch_bounds__(256) void gemmG_mfma(const float* __restrict__ h,
                                                  const unsigned short* __restrict__ Wfrag,
                                                  float* __restrict__ G, int n_nodes) {
    __shared__ unsigned short As[32][136];
    int tid = threadIdx.x;
    int n0 = blockIdx.x * 32;
    for (int i = tid; i < 512; i += 256) {  // 32 rows x 16 chunks of 8
        int row = i >> 4, c8 = i & 15;
        int n = n0 + row;
        union { unsigned short u[8]; s8v v; } t;
        if (n < n_nodes) {
            const float* p = &h[(size_t)n * 128 + c8 * 8];
            float4 lo = *(const float4*)p;
            float4 hi = *(const float4*)(p + 4);
            t.u[0] = f2bf(lo.x); t.u[1] = f2bf(lo.y); t.u[2] = f2bf(lo.z); t.u[3] = f2bf(lo.w);
            t.u[4] = f2bf(hi.x); t.u[5] = f2bf(hi.y); t.u[6] = f2bf(hi.z); t.u[7] = f2bf(hi.w);
        } else {
#pragma unroll
            for (int j = 0; j < 8; ++j) t.u[j] = 0;
        }
        *(s8v*)&As[row][c8 * 8] = t.v;
    }
    __syncthreads();

    int wave = tid >> 6, lane = tid & 63;
    int rt = wave & 1, ch = wave >> 1;
    int m = lane & 15, q = lane >> 4;

    f4v acc[4];
#pragma unroll
    for (int c = 0; c < 4; ++c) acc[c] = (f4v){0.f, 0.f, 0.f, 0.f};

#pragma unroll
    for (int kt = 0; kt < 4; ++kt) {
        s8v a = *(const s8v*)&As[rt * 16 + m][kt * 32 + q * 8];
#pragma unroll
        for (int c = 0; c < 4; ++c) {
            int ctg = ch * 4 + c;
            s8v b = *(const s8v*)&Wfrag[(((size_t)kt * 8 + ctg) * 64 + lane) * 8];
            acc[c] = __builtin_amdgcn_mfma_f32_16x16x32_bf16(a, b, acc[c], 0, 0, 0);
        }
    }

#pragma unroll
    for (int c = 0; c < 4; ++c) {
        int col = ch * 64 + c * 16 + m;
#pragma unroll
        for (int r = 0; r < 4; ++r) {
            int n = n0 + rt * 16 + q * 4 + r;
            if (n < n_nodes) G[(size_t)n * 128 + col] = acc[c][r];
        }
    }
}

// ---------------- layer-2 epilogue: 47-wide aggregate + log_softmax ----------------
__global__ __launch_bounds__(256) void out_kernel(const float* __restrict__ G,
                                                  const int* __restrict__ rowptr,
                                                  const int* __restrict__ ssrc,
                                                  const float* __restrict__ inv_deg,
                                                  const float* __restrict__ bias,
                                                  float* __restrict__ out, int n_nodes) {
    int lane = threadIdx.x & 63;
    int n = blockIdx.x * 4 + (threadIdx.x >> 6);
    if (n >= n_nodes) return;
    bool ok = lane < 47;
    int col = ok ? lane : 46;
    int e0 = rowptr[n], e1 = rowptr[n + 1];
    float acc = 0.f;
    int e = e0;
    for (; e + 3 < e1; e += 4) {
        int s0 = ssrc[e], s1 = ssrc[e + 1], s2 = ssrc[e + 2], s3 = ssrc[e + 3];
        float g0 = G[(size_t)s0 * 128 + col];
        float g1 = G[(size_t)s1 * 128 + col];
        float g2 = G[(size_t)s2 * 128 + col];
        float g3 = G[(size_t)s3 * 128 + col];
        acc += g0 + g1 + g2 + g3;
    }
    for (; e < e1; ++e) acc += G[(size_t)ssrc[e] * 128 + col];

    float v = -INFINITY;
    if (ok) v = acc * inv_deg[n] + G[(size_t)n * 128 + 64 + col] + bias[col];

    float m = v;
#pragma unroll
    for (int off = 32; off >= 1; off >>= 1)
        m = fmaxf(m, __shfl_xor(m, off, 64));
    float s = ok ? __expf(v - m) : 0.f;
#pragma unroll
    for (int off = 32; off >= 1; off >>= 1)
        s += __shfl_xor(s, off, 64);
    float ls = __logf(s);
    if (ok) out[(size_t)n * 47 + lane] = v - m - ls;
}

// ---------------- launch ----------------

extern "C" void kernel_launch(void* const* d_in, const int* in_sizes, int n_in,
                              void* d_out, int out_size, void* d_ws, size_t ws_size,
                              hipStream_t stream) {
    const float* x   = (const float*)d_in[0];
    const int*   src = (const int*)d_in[1];
    const int*   dst = (const int*)d_in[2];
    const float* Wl0 = (const float*)d_in[3];
    const float* bl0 = (const float*)d_in[4];
    const float* Wr0 = (const float*)d_in[5];
    const float* Wl1 = (const float*)d_in[6];
    const float* bl1 = (const float*)d_in[7];
    const float* Wr1 = (const float*)d_in[8];
    const float* Wl2 = (const float*)d_in[9];
    const float* bl2 = (const float*)d_in[10];
    const float* Wr2 = (const float*)d_in[11];
    float* out = (float*)d_out;

    int N = in_sizes[0] / 128;
    int E = in_sizes[1];
    int nBuckets = (N + 255) >> BUCKET_SHIFT;

    char* ws = (char*)d_ws;
    size_t off = 0;
    auto alloc = [&](size_t bytes) -> char* {
        char* p = ws + off;
        off += (bytes + 255) & ~(size_t)255;
        return p;
    };
    int*   cnt    = (int*)alloc((size_t)N * 4);
    int*   rowptr = (int*)alloc((size_t)(N + 1) * 4);
    float* invd   = (float*)alloc((size_t)N * 4);
    int*   ssrc   = (int*)alloc((size_t)E * 4);
    float* aggb   = (float*)alloc((size_t)N * 128 * 4);  // reused: interm (CSR) then G
    float* hbuf   = (float*)alloc((size_t)N * 128 * 4);
    int*   bsum   = (int*)alloc(256 * 4);
    int*   gcur   = (int*)alloc(512 * 4);
    unsigned short* wf0 = (unsigned short*)alloc(32768 * 2);
    unsigned short* wf1 = (unsigned short*)alloc(32768 * 2);
    unsigned short* wf2 = (unsigned short*)alloc(16384 * 2);

    int2* interm = (int2*)aggb;

    int nScanBlocks = (N + 2047) / 2048;

    hipMemsetAsync(cnt, 0, (size_t)N * 4, stream);
    hist_kernel<<<(E + 255) / 256, 256, 0, stream>>>(dst, cnt, E);
    block_sum_kernel<<<nScanBlocks, 256, 0, stream>>>(cnt, bsum, N);
    scan_bsum_kernel<<<1, 64, 0, stream>>>(bsum, nScanBlocks);
    scan_write_kernel<<<nScanBlocks, 256, 0, stream>>>(cnt, bsum, rowptr, invd, N);
    init_gcursor_kernel<<<(nBuckets + 255) / 256, 256, 0, stream>>>(rowptr, gcur, nBuckets);
    bucket_scatter_kernel<<<(E + 16383) / 16384, 256, 0, stream>>>(src, dst, gcur, interm,
                                                                   E, nBuckets);
    bucket_sort_kernel<<<nBuckets, 256, 0, stream>>>(interm, rowptr, ssrc, N);
    pack01_kernel<<<128, 256, 0, stream>>>(Wl0, Wr0, wf0);
    pack01_kernel<<<128, 256, 0, stream>>>(Wl1, Wr1, wf1);
    packl2_kernel<<<64, 256, 0, stream>>>(Wl2, Wr2, wf2);

    int aggGrid  = (N + 7) / 8;
    int gemmGrid = (N + 31) / 32;

    // layer 0: x -> hbuf
    agg_kernel<<<aggGrid, 256, 0, stream>>>((const float4*)x, rowptr, ssrc, invd,
                                            (float4*)aggb, N);
    gemm128_mfma<<<gemmGrid, 256, 0, stream>>>(aggb, x, wf0, bl0, hbuf, N);

    // layer 1: hbuf -> hbuf (in-place safe: rows staged in LDS before stores)
    agg_kernel<<<aggGrid, 256, 0, stream>>>((const float4*)hbuf, rowptr, ssrc, invd,
                                            (float4*)aggb, N);
    gemm128_mfma<<<gemmGrid, 256, 0, stream>>>(aggb, hbuf, wf1, bl1, hbuf, N);

    // layer 2 (reordered): G = hbuf @ [Wl2|Wr2], then 47-wide aggregate + log_softmax
    float* G = aggb;
    gemmG_mfma<<<gemmGrid, 256, 0, stream>>>(hbuf, wf2, G, N);
    out_kernel<<<(N + 3) / 4, 256, 0, stream>>>(G, rowptr, ssrc, invd, bl2, out, N);
}

// Round 7
// 524.303 us; speedup vs baseline: 2.4284x; 1.2111x over previous
//
#include <hip/hip_runtime.h>
#include <math.h>

#define BUCKET_SHIFT 8  // 256 nodes per bucket

typedef short s8v __attribute__((ext_vector_type(8)));   // 8 bf16 (4 VGPRs)
typedef float f4v __attribute__((ext_vector_type(4)));   // 4 fp32 acc
typedef unsigned short u16;

__device__ inline u16 f2bf(float f) {  // RNE fp32->bf16
    unsigned u = __float_as_uint(f);
    return (u16)((u + 0x7FFFu + ((u >> 16) & 1u)) >> 16);
}
__device__ inline float bf2f(u16 s) { return __uint_as_float(((unsigned)s) << 16); }

// ---------------- CSR build ----------------

__global__ void hist_kernel(const int* __restrict__ dst, int* __restrict__ cnt, int n_edges) {
    int e = blockIdx.x * blockDim.x + threadIdx.x;
    if (e < n_edges) atomicAdd(&cnt[dst[e]], 1);
}

__global__ __launch_bounds__(256) void block_sum_kernel(const int* __restrict__ cnt,
                                                        int* __restrict__ bsum, int n) {
    int tid = threadIdx.x;
    int i0 = blockIdx.x * 2048 + tid * 8;
    int s = 0;
#pragma unroll
    for (int j = 0; j < 8; ++j) {
        int i = i0 + j;
        if (i < n) s += cnt[i];
    }
#pragma unroll
    for (int off = 32; off >= 1; off >>= 1) s += __shfl_xor(s, off, 64);
    __shared__ int ws[4];
    if ((tid & 63) == 0) ws[tid >> 6] = s;
    __syncthreads();
    if (tid == 0) bsum[blockIdx.x] = ws[0] + ws[1] + ws[2] + ws[3];
}

__global__ void scan_bsum_kernel(int* __restrict__ bsum, int nb) {
    if (blockIdx.x == 0 && threadIdx.x == 0) {
        int run = 0;
        for (int i = 0; i < nb; ++i) {
            int v = bsum[i];
            bsum[i] = run;
            run += v;
        }
    }
}

__global__ __launch_bounds__(256) void scan_write_kernel(const int* __restrict__ cnt,
                                                         const int* __restrict__ bsum,
                                                         int* __restrict__ rowptr,
                                                         float* __restrict__ invd, int n) {
    int tid = threadIdx.x;
    int i0 = blockIdx.x * 2048 + tid * 8;
    int vals[8];
    int s = 0;
#pragma unroll
    for (int j = 0; j < 8; ++j) {
        int i = i0 + j;
        vals[j] = (i < n) ? cnt[i] : 0;
        s += vals[j];
    }
    int lane = tid & 63, wave = tid >> 6;
    int v = s;
#pragma unroll
    for (int off = 1; off < 64; off <<= 1) {
        int t = __shfl_up(v, off, 64);
        if (lane >= off) v += t;
    }
    __shared__ int wsum[4], woff[4];
    if (lane == 63) wsum[wave] = v;
    __syncthreads();
    if (tid == 0) {
        int run = 0;
#pragma unroll
        for (int w = 0; w < 4; ++w) { woff[w] = run; run += wsum[w]; }
    }
    __syncthreads();
    int run = bsum[blockIdx.x] + woff[wave] + (v - s);
#pragma unroll
    for (int j = 0; j < 8; ++j) {
        int i = i0 + j;
        if (i < n) {
            int c = vals[j];
            invd[i] = c > 0 ? 1.0f / (float)c : 0.0f;
            rowptr[i + 1] = run + c;
            run += c;
        }
    }
    if (blockIdx.x == 0 && tid == 0) rowptr[0] = 0;
}

__global__ void init_gcursor_kernel(const int* __restrict__ rowptr, int* __restrict__ gcursor,
                                    int nbuckets) {
    int j = blockIdx.x * blockDim.x + threadIdx.x;
    if (j < nbuckets) gcursor[j] = rowptr[j << BUCKET_SHIFT];
}

__global__ __launch_bounds__(256) void bucket_scatter_kernel(const int* __restrict__ src,
                                                             const int* __restrict__ dst,
                                                             int* __restrict__ gcursor,
                                                             int2* __restrict__ interm,
                                                             int n_edges, int nbuckets) {
    __shared__ int hist[512];
    __shared__ int gbase[512];
    int tid = threadIdx.x;
    for (int j = tid; j < nbuckets; j += 256) hist[j] = 0;
    __syncthreads();
    int e0 = blockIdx.x * 16384;
    int e1 = min(e0 + 16384, n_edges);
    for (int e = e0 + tid; e < e1; e += 256)
        atomicAdd(&hist[dst[e] >> BUCKET_SHIFT], 1);
    __syncthreads();
    for (int j = tid; j < nbuckets; j += 256) {
        int c = hist[j];
        gbase[j] = c > 0 ? atomicAdd(&gcursor[j], c) : 0;
        hist[j] = 0;
    }
    __syncthreads();
    for (int e = e0 + tid; e < e1; e += 256) {
        int d = dst[e];
        int s = src[e];
        int j = d >> BUCKET_SHIFT;
        int p = atomicAdd(&hist[j], 1);
        interm[gbase[j] + p] = make_int2(d, s);
    }
}

__global__ __launch_bounds__(256) void bucket_sort_kernel(const int2* __restrict__ interm,
                                                          const int* __restrict__ rowptr,
                                                          int* __restrict__ ssrc, int n_nodes) {
    __shared__ int cur[256];
    int tid = threadIdx.x;
    int nb0 = blockIdx.x << BUCKET_SHIFT;
    int nEnd = min(nb0 + 256, n_nodes);
    int base = rowptr[nb0];
    int end = rowptr[nEnd];
    if (nb0 + tid < n_nodes) cur[tid] = rowptr[nb0 + tid] - base;
    __syncthreads();
    for (int e = base + tid; e < end; e += 256) {
        int2 p = interm[e];
        int pos = atomicAdd(&cur[p.x - nb0], 1);
        ssrc[base + pos] = p.y;
    }
}

// ---------------- x -> bf16 ----------------
__global__ __launch_bounds__(256) void convert_kernel(const float* __restrict__ x,
                                                      u16* __restrict__ xb, long total8) {
    long i = (long)blockIdx.x * 256 + threadIdx.x;  // index of 8-elem chunk
    if (i >= total8) return;
    const float* p = &x[i * 8];
    float4 lo = *(const float4*)p;
    float4 hi = *(const float4*)(p + 4);
    union { u16 u[8]; s8v v; } t;
    t.u[0] = f2bf(lo.x); t.u[1] = f2bf(lo.y); t.u[2] = f2bf(lo.z); t.u[3] = f2bf(lo.w);
    t.u[4] = f2bf(hi.x); t.u[5] = f2bf(hi.y); t.u[6] = f2bf(hi.z); t.u[7] = f2bf(hi.w);
    *(s8v*)&xb[i * 8] = t.v;
}

// ---------------- weight packing into MFMA fragment order ----------------
__global__ void pack01_kernel(const float* __restrict__ Wl, const float* __restrict__ Wr,
                              u16* __restrict__ out) {
    int idx = blockIdx.x * 256 + threadIdx.x;  // 256*128
    if (idx >= 32768) return;
    int k = idx >> 7, c = idx & 127;
    float v = (k < 128) ? Wl[k * 128 + c] : Wr[(k - 128) * 128 + c];
    int kt = k >> 5, q = (k >> 3) & 3, j = k & 7, ct = c >> 4, n = c & 15;
    out[(((kt * 8 + ct) * 64 + q * 16 + n) << 3) + j] = f2bf(v);
}

__global__ void packl2_kernel(const float* __restrict__ Wl, const float* __restrict__ Wr,
                              u16* __restrict__ out) {
    int idx = blockIdx.x * 256 + threadIdx.x;  // 128*128
    if (idx >= 16384) return;
    int k = idx >> 7, c = idx & 127;
    float v = 0.f;
    if (c < 47) v = Wl[k * 47 + c];
    else if (c >= 64 && c < 111) v = Wr[k * 47 + (c - 64)];
    int kt = k >> 5, q = (k >> 3) & 3, j = k & 7, ct = c >> 4, n = c & 15;
    out[(((kt * 8 + ct) * 64 + q * 16 + n) << 3) + j] = f2bf(v);
}

// ---------------- mean aggregation over bf16 rows (256 B/row) ----------------
// 8 nodes per 256-thread block; 32 lanes x uint2 (4 bf16) cover 128 features.
__global__ __launch_bounds__(256) void agg_kernel(const uint2* __restrict__ h2,
                                                  const int* __restrict__ rowptr,
                                                  const int* __restrict__ ssrc,
                                                  const float* __restrict__ inv_deg,
                                                  uint2* __restrict__ aggout, int n_nodes) {
    int tid = threadIdx.x;
    int d = tid & 31;
    int n = blockIdx.x * 8 + (tid >> 5);
    if (n >= n_nodes) return;
    int e0 = rowptr[n], e1 = rowptr[n + 1];
    float a0 = 0.f, a1 = 0.f, a2 = 0.f, a3 = 0.f;
    int e = e0;
    for (; e + 3 < e1; e += 4) {
        int s0 = ssrc[e], s1 = ssrc[e + 1], s2 = ssrc[e + 2], s3 = ssrc[e + 3];
        uint2 v0 = h2[(size_t)s0 * 32 + d];
        uint2 v1 = h2[(size_t)s1 * 32 + d];
        uint2 v2 = h2[(size_t)s2 * 32 + d];
        uint2 v3 = h2[(size_t)s3 * 32 + d];
        a0 += __uint_as_float(v0.x << 16) + __uint_as_float(v1.x << 16) +
              __uint_as_float(v2.x << 16) + __uint_as_float(v3.x << 16);
        a1 += __uint_as_float(v0.x & 0xffff0000u) + __uint_as_float(v1.x & 0xffff0000u) +
              __uint_as_float(v2.x & 0xffff0000u) + __uint_as_float(v3.x & 0xffff0000u);
        a2 += __uint_as_float(v0.y << 16) + __uint_as_float(v1.y << 16) +
              __uint_as_float(v2.y << 16) + __uint_as_float(v3.y << 16);
        a3 += __uint_as_float(v0.y & 0xffff0000u) + __uint_as_float(v1.y & 0xffff0000u) +
              __uint_as_float(v2.y & 0xffff0000u) + __uint_as_float(v3.y & 0xffff0000u);
    }
    for (; e < e1; ++e) {
        uint2 vv = h2[(size_t)ssrc[e] * 32 + d];
        a0 += __uint_as_float(vv.x << 16);
        a1 += __uint_as_float(vv.x & 0xffff0000u);
        a2 += __uint_as_float(vv.y << 16);
        a3 += __uint_as_float(vv.y & 0xffff0000u);
    }
    float w = inv_deg[n];
    uint2 o;
    o.x = (unsigned)f2bf(a0 * w) | ((unsigned)f2bf(a1 * w) << 16);
    o.y = (unsigned)f2bf(a2 * w) | ((unsigned)f2bf(a3 * w) << 16);
    aggout[(size_t)n * 32 + d] = o;
}

// ---------------- MFMA GEMM: out = relu([agg|h] @ Wfrag + b) bf16, K=256, N=128 ----------------
__global__ __launch_bounds__(256) void gemm128_mfma(const u16* __restrict__ agg,
                                                    const u16* __restrict__ h,
                                                    const u16* __restrict__ Wfrag,
                                                    const float* __restrict__ bias,
                                                    u16* __restrict__ out, int n_nodes) {
    __shared__ u16 As[32][264];
    int tid = threadIdx.x;
    int n0 = blockIdx.x * 32;
    for (int i = tid; i < 1024; i += 256) {  // 32 rows x 32 chunks of 8
        int row = i >> 5, c8 = i & 31;
        int n = n0 + row;
        s8v t = (s8v){0, 0, 0, 0, 0, 0, 0, 0};
        if (n < n_nodes)
            t = (c8 < 16) ? *(const s8v*)&agg[(size_t)n * 128 + c8 * 8]
                          : *(const s8v*)&h[(size_t)n * 128 + (c8 - 16) * 8];
        *(s8v*)&As[row][c8 * 8] = t;
    }
    __syncthreads();

    int wave = tid >> 6, lane = tid & 63;
    int rt = wave & 1, ch = wave >> 1;
    int m = lane & 15, q = lane >> 4;

    f4v acc[4];
#pragma unroll
    for (int c = 0; c < 4; ++c) acc[c] = (f4v){0.f, 0.f, 0.f, 0.f};

#pragma unroll
    for (int kt = 0; kt < 8; ++kt) {
        s8v a = *(const s8v*)&As[rt * 16 + m][kt * 32 + q * 8];
#pragma unroll
        for (int c = 0; c < 4; ++c) {
            int ctg = ch * 4 + c;
            s8v b = *(const s8v*)&Wfrag[(((size_t)kt * 8 + ctg) * 64 + lane) * 8];
            acc[c] = __builtin_amdgcn_mfma_f32_16x16x32_bf16(a, b, acc[c], 0, 0, 0);
        }
    }

#pragma unroll
    for (int c = 0; c < 4; ++c) {
        int col = ch * 64 + c * 16 + m;
        float bc = bias[col];
#pragma unroll
        for (int r = 0; r < 4; ++r) {
            int n = n0 + rt * 16 + q * 4 + r;
            if (n < n_nodes)
                out[(size_t)n * 128 + col] = f2bf(fmaxf(acc[c][r] + bc, 0.f));
        }
    }
}

// ---------------- MFMA GEMM: G = h @ Wfrag2 bf16, K=128, N=128 ----------------
__global__ __launch_bounds__(256) void gemmG_mfma(const u16* __restrict__ h,
                                                  const u16* __restrict__ Wfrag,
                                                  u16* __restrict__ G, int n_nodes) {
    __shared__ u16 As[32][136];
    int tid = threadIdx.x;
    int n0 = blockIdx.x * 32;
    for (int i = tid; i < 512; i += 256) {  // 32 rows x 16 chunks of 8
        int row = i >> 4, c8 = i & 15;
        int n = n0 + row;
        s8v t = (s8v){0, 0, 0, 0, 0, 0, 0, 0};
        if (n < n_nodes) t = *(const s8v*)&h[(size_t)n * 128 + c8 * 8];
        *(s8v*)&As[row][c8 * 8] = t;
    }
    __syncthreads();

    int wave = tid >> 6, lane = tid & 63;
    int rt = wave & 1, ch = wave >> 1;
    int m = lane & 15, q = lane >> 4;

    f4v acc[4];
#pragma unroll
    for (int c = 0; c < 4; ++c) acc[c] = (f4v){0.f, 0.f, 0.f, 0.f};

#pragma unroll
    for (int kt = 0; kt < 4; ++kt) {
        s8v a = *(const s8v*)&As[rt * 16 + m][kt * 32 + q * 8];
#pragma unroll
        for (int c = 0; c < 4; ++c) {
            int ctg = ch * 4 + c;
            s8v b = *(const s8v*)&Wfrag[(((size_t)kt * 8 + ctg) * 64 + lane) * 8];
            acc[c] = __builtin_amdgcn_mfma_f32_16x16x32_bf16(a, b, acc[c], 0, 0, 0);
        }
    }

#pragma unroll
    for (int c = 0; c < 4; ++c) {
        int col = ch * 64 + c * 16 + m;
#pragma unroll
        for (int r = 0; r < 4; ++r) {
            int n = n0 + rt * 16 + q * 4 + r;
            if (n < n_nodes) G[(size_t)n * 128 + col] = f2bf(acc[c][r]);
        }
    }
}

// ---------------- layer-2 epilogue: 47-wide aggregate + log_softmax ----------------
__global__ __launch_bounds__(256) void out_kernel(const u16* __restrict__ G,
                                                  const int* __restrict__ rowptr,
                                                  const int* __restrict__ ssrc,
                                                  const float* __restrict__ inv_deg,
                                                  const float* __restrict__ bias,
                                                  float* __restrict__ out, int n_nodes) {
    int lane = threadIdx.x & 63;
    int n = blockIdx.x * 4 + (threadIdx.x >> 6);
    if (n >= n_nodes) return;
    bool ok = lane < 47;
    int col = ok ? lane : 46;
    int e0 = rowptr[n], e1 = rowptr[n + 1];
    float acc = 0.f;
    int e = e0;
    for (; e + 3 < e1; e += 4) {
        int s0 = ssrc[e], s1 = ssrc[e + 1], s2 = ssrc[e + 2], s3 = ssrc[e + 3];
        float g0 = bf2f(G[(size_t)s0 * 128 + col]);
        float g1 = bf2f(G[(size_t)s1 * 128 + col]);
        float g2 = bf2f(G[(size_t)s2 * 128 + col]);
        float g3 = bf2f(G[(size_t)s3 * 128 + col]);
        acc += g0 + g1 + g2 + g3;
    }
    for (; e < e1; ++e) acc += bf2f(G[(size_t)ssrc[e] * 128 + col]);

    float v = -INFINITY;
    if (ok) v = acc * inv_deg[n] + bf2f(G[(size_t)n * 128 + 64 + col]) + bias[col];

    float m = v;
#pragma unroll
    for (int off = 32; off >= 1; off >>= 1)
        m = fmaxf(m, __shfl_xor(m, off, 64));
    float s = ok ? __expf(v - m) : 0.f;
#pragma unroll
    for (int off = 32; off >= 1; off >>= 1)
        s += __shfl_xor(s, off, 64);
    float ls = __logf(s);
    if (ok) out[(size_t)n * 47 + lane] = v - m - ls;
}

// ---------------- launch ----------------

extern "C" void kernel_launch(void* const* d_in, const int* in_sizes, int n_in,
                              void* d_out, int out_size, void* d_ws, size_t ws_size,
                              hipStream_t stream) {
    const float* x   = (const float*)d_in[0];
    const int*   src = (const int*)d_in[1];
    const int*   dst = (const int*)d_in[2];
    const float* Wl0 = (const float*)d_in[3];
    const float* bl0 = (const float*)d_in[4];
    const float* Wr0 = (const float*)d_in[5];
    const float* Wl1 = (const float*)d_in[6];
    const float* bl1 = (const float*)d_in[7];
    const float* Wr1 = (const float*)d_in[8];
    const float* Wl2 = (const float*)d_in[9];
    const float* bl2 = (const float*)d_in[10];
    const float* Wr2 = (const float*)d_in[11];
    float* out = (float*)d_out;

    int N = in_sizes[0] / 128;
    int E = in_sizes[1];
    int nBuckets = (N + 255) >> BUCKET_SHIFT;

    char* ws = (char*)d_ws;
    size_t off = 0;
    auto alloc = [&](size_t bytes) -> char* {
        char* p = ws + off;
        off += (bytes + 255) & ~(size_t)255;
        return p;
    };
    int*   cnt    = (int*)alloc((size_t)N * 4);
    int*   rowptr = (int*)alloc((size_t)(N + 1) * 4);
    float* invd   = (float*)alloc((size_t)N * 4);
    int*   ssrc   = (int*)alloc((size_t)E * 4);
    u16*   xb     = (u16*)alloc((size_t)N * 128 * 2);
    u16*   aggb   = (u16*)alloc((size_t)N * 128 * 2);   // agg out, later G
    u16*   hbuf   = (u16*)alloc((size_t)N * 128 * 2);
    int2*  interm = (int2*)alloc((size_t)E * 8);        // CSR pairs (12.8 MB)
    int*   bsum   = (int*)alloc(256 * 4);
    int*   gcur   = (int*)alloc(512 * 4);
    u16*   wf0    = (u16*)alloc(32768 * 2);
    u16*   wf1    = (u16*)alloc(32768 * 2);
    u16*   wf2    = (u16*)alloc(16384 * 2);

    int nScanBlocks = (N + 2047) / 2048;

    hipMemsetAsync(cnt, 0, (size_t)N * 4, stream);
    hist_kernel<<<(E + 255) / 256, 256, 0, stream>>>(dst, cnt, E);
    block_sum_kernel<<<nScanBlocks, 256, 0, stream>>>(cnt, bsum, N);
    scan_bsum_kernel<<<1, 64, 0, stream>>>(bsum, nScanBlocks);
    scan_write_kernel<<<nScanBlocks, 256, 0, stream>>>(cnt, bsum, rowptr, invd, N);
    init_gcursor_kernel<<<(nBuckets + 255) / 256, 256, 0, stream>>>(rowptr, gcur, nBuckets);
    bucket_scatter_kernel<<<(E + 16383) / 16384, 256, 0, stream>>>(src, dst, gcur, interm,
                                                                   E, nBuckets);
    bucket_sort_kernel<<<nBuckets, 256, 0, stream>>>(interm, rowptr, ssrc, N);
    long total8 = (long)N * 16;  // N*128/8
    convert_kernel<<<(int)((total8 + 255) / 256), 256, 0, stream>>>(x, xb, total8);
    pack01_kernel<<<128, 256, 0, stream>>>(Wl0, Wr0, wf0);
    pack01_kernel<<<128, 256, 0, stream>>>(Wl1, Wr1, wf1);
    packl2_kernel<<<64, 256, 0, stream>>>(Wl2, Wr2, wf2);

    int aggGrid  = (N + 7) / 8;
    int gemmGrid = (N + 31) / 32;

    // layer 0: xb -> hbuf
    agg_kernel<<<aggGrid, 256, 0, stream>>>((const uint2*)xb, rowptr, ssrc, invd,
                                            (uint2*)aggb, N);
    gemm128_mfma<<<gemmGrid, 256, 0, stream>>>(aggb, xb, wf0, bl0, hbuf, N);

    // layer 1: hbuf -> hbuf (in-place safe: rows staged in LDS before stores)
    agg_kernel<<<aggGrid, 256, 0, stream>>>((const uint2*)hbuf, rowptr, ssrc, invd,
                                            (uint2*)aggb, N);
    gemm128_mfma<<<gemmGrid, 256, 0, stream>>>(aggb, hbuf, wf1, bl1, hbuf, N);

    // layer 2 (reordered): G = hbuf @ [Wl2|Wr2] (bf16), then 47-wide agg + log_softmax
    u16* G = aggb;
    gemmG_mfma<<<gemmGrid, 256, 0, stream>>>(hbuf, wf2, G, N);
    out_kernel<<<(N + 3) / 4, 256, 0, stream>>>(G, rowptr, ssrc, invd, bl2, out, N);
}

// Round 8
// 496.882 us; speedup vs baseline: 2.5624x; 1.0552x over previous
//
#include <hip/hip_runtime.h>
#include <math.h>

#define BUCKET_SHIFT 8  // 256 nodes per bucket

typedef short s8v __attribute__((ext_vector_type(8)));   // 8 bf16 (4 VGPRs)
typedef float f4v __attribute__((ext_vector_type(4)));   // 4 fp32 acc
typedef unsigned short u16;

__device__ inline u16 f2bf(float f) {  // RNE fp32->bf16
    unsigned u = __float_as_uint(f);
    return (u16)((u + 0x7FFFu + ((u >> 16) & 1u)) >> 16);
}
__device__ inline float bf2f(u16 s) { return __uint_as_float(((unsigned)s) << 16); }

// ---------------- CSR build ----------------

__global__ void hist_kernel(const int* __restrict__ dst, int* __restrict__ cnt, int n_edges) {
    int e = blockIdx.x * blockDim.x + threadIdx.x;
    if (e < n_edges) atomicAdd(&cnt[dst[e]], 1);
}

__global__ __launch_bounds__(256) void block_sum_kernel(const int* __restrict__ cnt,
                                                        int* __restrict__ bsum, int n) {
    int tid = threadIdx.x;
    int i0 = blockIdx.x * 2048 + tid * 8;
    int s = 0;
#pragma unroll
    for (int j = 0; j < 8; ++j) {
        int i = i0 + j;
        if (i < n) s += cnt[i];
    }
#pragma unroll
    for (int off = 32; off >= 1; off >>= 1) s += __shfl_xor(s, off, 64);
    __shared__ int ws[4];
    if ((tid & 63) == 0) ws[tid >> 6] = s;
    __syncthreads();
    if (tid == 0) bsum[blockIdx.x] = ws[0] + ws[1] + ws[2] + ws[3];
}

__global__ void scan_bsum_kernel(int* __restrict__ bsum, int nb) {
    if (blockIdx.x == 0 && threadIdx.x == 0) {
        int run = 0;
        for (int i = 0; i < nb; ++i) {
            int v = bsum[i];
            bsum[i] = run;
            run += v;
        }
    }
}

__global__ __launch_bounds__(256) void scan_write_kernel(const int* __restrict__ cnt,
                                                         const int* __restrict__ bsum,
                                                         int* __restrict__ rowptr,
                                                         float* __restrict__ invd, int n) {
    int tid = threadIdx.x;
    int i0 = blockIdx.x * 2048 + tid * 8;
    int vals[8];
    int s = 0;
#pragma unroll
    for (int j = 0; j < 8; ++j) {
        int i = i0 + j;
        vals[j] = (i < n) ? cnt[i] : 0;
        s += vals[j];
    }
    int lane = tid & 63, wave = tid >> 6;
    int v = s;
#pragma unroll
    for (int off = 1; off < 64; off <<= 1) {
        int t = __shfl_up(v, off, 64);
        if (lane >= off) v += t;
    }
    __shared__ int wsum[4], woff[4];
    if (lane == 63) wsum[wave] = v;
    __syncthreads();
    if (tid == 0) {
        int run = 0;
#pragma unroll
        for (int w = 0; w < 4; ++w) { woff[w] = run; run += wsum[w]; }
    }
    __syncthreads();
    int run = bsum[blockIdx.x] + woff[wave] + (v - s);
#pragma unroll
    for (int j = 0; j < 8; ++j) {
        int i = i0 + j;
        if (i < n) {
            int c = vals[j];
            invd[i] = c > 0 ? 1.0f / (float)c : 0.0f;
            rowptr[i + 1] = run + c;
            run += c;
        }
    }
    if (blockIdx.x == 0 && tid == 0) rowptr[0] = 0;
}

__global__ void init_gcursor_kernel(const int* __restrict__ rowptr, int* __restrict__ gcursor,
                                    int nbuckets) {
    int j = blockIdx.x * blockDim.x + threadIdx.x;
    if (j < nbuckets) gcursor[j] = rowptr[j << BUCKET_SHIFT];
}

// interm entry: (src << 8) | (dst & 255); src < 2^24, bucket id = implicit by position
__global__ __launch_bounds__(256) void bucket_scatter_kernel(const int* __restrict__ src,
                                                             const int* __restrict__ dst,
                                                             int* __restrict__ gcursor,
                                                             unsigned* __restrict__ interm,
                                                             int n_edges, int nbuckets) {
    __shared__ int hist[512];
    __shared__ int gbase[512];
    int tid = threadIdx.x;
    for (int j = tid; j < nbuckets; j += 256) hist[j] = 0;
    __syncthreads();
    int e0 = blockIdx.x * 16384;
    int e1 = min(e0 + 16384, n_edges);
    for (int e = e0 + tid; e < e1; e += 256)
        atomicAdd(&hist[dst[e] >> BUCKET_SHIFT], 1);
    __syncthreads();
    for (int j = tid; j < nbuckets; j += 256) {
        int c = hist[j];
        gbase[j] = c > 0 ? atomicAdd(&gcursor[j], c) : 0;
        hist[j] = 0;
    }
    __syncthreads();
    for (int e = e0 + tid; e < e1; e += 256) {
        int d = dst[e];
        int s = src[e];
        int j = d >> BUCKET_SHIFT;
        int p = atomicAdd(&hist[j], 1);
        interm[gbase[j] + p] = ((unsigned)s << 8) | (unsigned)(d & 255);
    }
}

__global__ __launch_bounds__(256) void bucket_sort_kernel(const unsigned* __restrict__ interm,
                                                          const int* __restrict__ rowptr,
                                                          int* __restrict__ ssrc, int n_nodes) {
    __shared__ int cur[256];
    int tid = threadIdx.x;
    int nb0 = blockIdx.x << BUCKET_SHIFT;
    int nEnd = min(nb0 + 256, n_nodes);
    int base = rowptr[nb0];
    int end = rowptr[nEnd];
    if (nb0 + tid < n_nodes) cur[tid] = rowptr[nb0 + tid] - base;
    __syncthreads();
    for (int e = base + tid; e < end; e += 256) {
        unsigned p = interm[e];
        int pos = atomicAdd(&cur[p & 255u], 1);
        ssrc[base + pos] = (int)(p >> 8);
    }
}

// ---------------- x -> bf16 ----------------
__global__ __launch_bounds__(256) void convert_kernel(const float* __restrict__ x,
                                                      u16* __restrict__ xb, long total8) {
    long i = (long)blockIdx.x * 256 + threadIdx.x;  // index of 8-elem chunk
    if (i >= total8) return;
    const float* p = &x[i * 8];
    float4 lo = *(const float4*)p;
    float4 hi = *(const float4*)(p + 4);
    union { u16 u[8]; s8v v; } t;
    t.u[0] = f2bf(lo.x); t.u[1] = f2bf(lo.y); t.u[2] = f2bf(lo.z); t.u[3] = f2bf(lo.w);
    t.u[4] = f2bf(hi.x); t.u[5] = f2bf(hi.y); t.u[6] = f2bf(hi.z); t.u[7] = f2bf(hi.w);
    *(s8v*)&xb[i * 8] = t.v;
}

// ---------------- weight packing into MFMA fragment order ----------------
__global__ void pack01_kernel(const float* __restrict__ Wl, const float* __restrict__ Wr,
                              u16* __restrict__ out) {
    int idx = blockIdx.x * 256 + threadIdx.x;  // 256*128
    if (idx >= 32768) return;
    int k = idx >> 7, c = idx & 127;
    float v = (k < 128) ? Wl[k * 128 + c] : Wr[(k - 128) * 128 + c];
    int kt = k >> 5, q = (k >> 3) & 3, j = k & 7, ct = c >> 4, n = c & 15;
    out[(((kt * 8 + ct) * 64 + q * 16 + n) << 3) + j] = f2bf(v);
}

__global__ void packl2_kernel(const float* __restrict__ Wl, const float* __restrict__ Wr,
                              u16* __restrict__ out) {
    int idx = blockIdx.x * 256 + threadIdx.x;  // 128*128
    if (idx >= 16384) return;
    int k = idx >> 7, c = idx & 127;
    float v = 0.f;
    if (c < 47) v = Wl[k * 47 + c];
    else if (c >= 64 && c < 111) v = Wr[k * 47 + (c - 64)];
    int kt = k >> 5, q = (k >> 3) & 3, j = k & 7, ct = c >> 4, n = c & 15;
    out[(((kt * 8 + ct) * 64 + q * 16 + n) << 3) + j] = f2bf(v);
}

// ---------------- fused SAGE layer: gather-agg -> LDS A-tile -> MFMA ----------------
// hout = relu([mean_agg(hin) | hin] @ Wfrag + b), all features bf16.
// hin/hout MUST be distinct buffers (gather reads arbitrary rows).
__global__ __launch_bounds__(256) void sage_layer_mfma(const uint2* __restrict__ hin2,
                                                       const int* __restrict__ rowptr,
                                                       const int* __restrict__ ssrc,
                                                       const float* __restrict__ invd,
                                                       const u16* __restrict__ Wfrag,
                                                       const float* __restrict__ bias,
                                                       u16* __restrict__ hout, int n_nodes) {
    __shared__ u16 As[32][264];
    int tid = threadIdx.x;
    int n0 = blockIdx.x * 32;
    int d = tid & 31, grp = tid >> 5;  // 8 groups of 32 lanes

    // phase 1: gather-aggregate rows n0..n0+31 into As cols 0..127 (bf16)
#pragma unroll
    for (int pass = 0; pass < 4; ++pass) {
        int row = pass * 8 + grp;
        int n = n0 + row;
        float a0 = 0.f, a1 = 0.f, a2 = 0.f, a3 = 0.f;
        if (n < n_nodes) {
            int e0 = rowptr[n], e1 = rowptr[n + 1];
            int e = e0;
            for (; e + 3 < e1; e += 4) {
                int s0 = ssrc[e], s1 = ssrc[e + 1], s2 = ssrc[e + 2], s3 = ssrc[e + 3];
                uint2 v0 = hin2[(size_t)s0 * 32 + d];
                uint2 v1 = hin2[(size_t)s1 * 32 + d];
                uint2 v2 = hin2[(size_t)s2 * 32 + d];
                uint2 v3 = hin2[(size_t)s3 * 32 + d];
                a0 += __uint_as_float(v0.x << 16) + __uint_as_float(v1.x << 16) +
                      __uint_as_float(v2.x << 16) + __uint_as_float(v3.x << 16);
                a1 += __uint_as_float(v0.x & 0xffff0000u) + __uint_as_float(v1.x & 0xffff0000u) +
                      __uint_as_float(v2.x & 0xffff0000u) + __uint_as_float(v3.x & 0xffff0000u);
                a2 += __uint_as_float(v0.y << 16) + __uint_as_float(v1.y << 16) +
                      __uint_as_float(v2.y << 16) + __uint_as_float(v3.y << 16);
                a3 += __uint_as_float(v0.y & 0xffff0000u) + __uint_as_float(v1.y & 0xffff0000u) +
                      __uint_as_float(v2.y & 0xffff0000u) + __uint_as_float(v3.y & 0xffff0000u);
            }
            for (; e < e1; ++e) {
                uint2 vv = hin2[(size_t)ssrc[e] * 32 + d];
                a0 += __uint_as_float(vv.x << 16);
                a1 += __uint_as_float(vv.x & 0xffff0000u);
                a2 += __uint_as_float(vv.y << 16);
                a3 += __uint_as_float(vv.y & 0xffff0000u);
            }
            float w = invd[n];
            a0 *= w; a1 *= w; a2 *= w; a3 *= w;
        }
        uint2 o;
        o.x = (unsigned)f2bf(a0) | ((unsigned)f2bf(a1) << 16);
        o.y = (unsigned)f2bf(a2) | ((unsigned)f2bf(a3) << 16);
        *(uint2*)&As[row][d * 4] = o;
    }

    // phase 2: stage self rows into As cols 128..255
    const u16* hin = (const u16*)hin2;
    for (int i = tid; i < 512; i += 256) {
        int row = i >> 4, c8 = i & 15;
        int n = n0 + row;
        s8v t = (s8v){0, 0, 0, 0, 0, 0, 0, 0};
        if (n < n_nodes) t = *(const s8v*)&hin[(size_t)n * 128 + c8 * 8];
        *(s8v*)&As[row][128 + c8 * 8] = t;
    }
    __syncthreads();

    // phase 3: MFMA, K=256
    int wave = tid >> 6, lane = tid & 63;
    int rt = wave & 1, ch = wave >> 1;
    int m = lane & 15, q = lane >> 4;

    f4v acc[4];
#pragma unroll
    for (int c = 0; c < 4; ++c) acc[c] = (f4v){0.f, 0.f, 0.f, 0.f};

#pragma unroll
    for (int kt = 0; kt < 8; ++kt) {
        s8v a = *(const s8v*)&As[rt * 16 + m][kt * 32 + q * 8];
#pragma unroll
        for (int c = 0; c < 4; ++c) {
            int ctg = ch * 4 + c;
            s8v b = *(const s8v*)&Wfrag[(((size_t)kt * 8 + ctg) * 64 + lane) * 8];
            acc[c] = __builtin_amdgcn_mfma_f32_16x16x32_bf16(a, b, acc[c], 0, 0, 0);
        }
    }

#pragma unroll
    for (int c = 0; c < 4; ++c) {
        int col = ch * 64 + c * 16 + m;
        float bc = bias[col];
#pragma unroll
        for (int r = 0; r < 4; ++r) {
            int n = n0 + rt * 16 + q * 4 + r;
            if (n < n_nodes)
                hout[(size_t)n * 128 + col] = f2bf(fmaxf(acc[c][r] + bc, 0.f));
        }
    }
}

// ---------------- MFMA GEMM: [Gn|Gs] = h @ Wfrag2 bf16, K=128 ----------------
// Gn = neighbor projection (cols 0..63, 47 real), Gs = self projection (cols 64..127).
__global__ __launch_bounds__(256) void gemmG_mfma(const u16* __restrict__ h,
                                                  const u16* __restrict__ Wfrag,
                                                  u16* __restrict__ Gn,
                                                  u16* __restrict__ Gs, int n_nodes) {
    __shared__ u16 As[32][136];
    int tid = threadIdx.x;
    int n0 = blockIdx.x * 32;
    for (int i = tid; i < 512; i += 256) {
        int row = i >> 4, c8 = i & 15;
        int n = n0 + row;
        s8v t = (s8v){0, 0, 0, 0, 0, 0, 0, 0};
        if (n < n_nodes) t = *(const s8v*)&h[(size_t)n * 128 + c8 * 8];
        *(s8v*)&As[row][c8 * 8] = t;
    }
    __syncthreads();

    int wave = tid >> 6, lane = tid & 63;
    int rt = wave & 1, ch = wave >> 1;
    int m = lane & 15, q = lane >> 4;

    f4v acc[4];
#pragma unroll
    for (int c = 0; c < 4; ++c) acc[c] = (f4v){0.f, 0.f, 0.f, 0.f};

#pragma unroll
    for (int kt = 0; kt < 4; ++kt) {
        s8v a = *(const s8v*)&As[rt * 16 + m][kt * 32 + q * 8];
#pragma unroll
        for (int c = 0; c < 4; ++c) {
            int ctg = ch * 4 + c;
            s8v b = *(const s8v*)&Wfrag[(((size_t)kt * 8 + ctg) * 64 + lane) * 8];
            acc[c] = __builtin_amdgcn_mfma_f32_16x16x32_bf16(a, b, acc[c], 0, 0, 0);
        }
    }

    u16* Gbase = (ch == 0) ? Gn : Gs;
#pragma unroll
    for (int c = 0; c < 4; ++c) {
        int col = c * 16 + m;  // 0..63 within the half
#pragma unroll
        for (int r = 0; r < 4; ++r) {
            int n = n0 + rt * 16 + q * 4 + r;
            if (n < n_nodes) Gbase[(size_t)n * 64 + col] = f2bf(acc[c][r]);
        }
    }
}

// ---------------- layer-2 epilogue: gather Gn (one 128B line/edge) + log_softmax ----------------
__global__ __launch_bounds__(256) void out_kernel(const u16* __restrict__ Gn,
                                                  const u16* __restrict__ Gs,
                                                  const int* __restrict__ rowptr,
                                                  const int* __restrict__ ssrc,
                                                  const float* __restrict__ inv_deg,
                                                  const float* __restrict__ bias,
                                                  float* __restrict__ out, int n_nodes) {
    int lane = threadIdx.x & 63;
    int n = blockIdx.x * 4 + (threadIdx.x >> 6);
    if (n >= n_nodes) return;
    bool ok = lane < 47;
    int e0 = rowptr[n], e1 = rowptr[n + 1];
    float acc = 0.f;
    int e = e0;
    for (; e + 3 < e1; e += 4) {
        int s0 = ssrc[e], s1 = ssrc[e + 1], s2 = ssrc[e + 2], s3 = ssrc[e + 3];
        float g0 = bf2f(Gn[(size_t)s0 * 64 + lane]);
        float g1 = bf2f(Gn[(size_t)s1 * 64 + lane]);
        float g2 = bf2f(Gn[(size_t)s2 * 64 + lane]);
        float g3 = bf2f(Gn[(size_t)s3 * 64 + lane]);
        acc += g0 + g1 + g2 + g3;
    }
    for (; e < e1; ++e) acc += bf2f(Gn[(size_t)ssrc[e] * 64 + lane]);

    float v = -INFINITY;
    if (ok) v = acc * inv_deg[n] + bf2f(Gs[(size_t)n * 64 + lane]) + bias[lane];

    float m = v;
#pragma unroll
    for (int off = 32; off >= 1; off >>= 1)
        m = fmaxf(m, __shfl_xor(m, off, 64));
    float s = ok ? __expf(v - m) : 0.f;
#pragma unroll
    for (int off = 32; off >= 1; off >>= 1)
        s += __shfl_xor(s, off, 64);
    float ls = __logf(s);
    if (ok) out[(size_t)n * 47 + lane] = v - m - ls;
}

// ---------------- launch ----------------

extern "C" void kernel_launch(void* const* d_in, const int* in_sizes, int n_in,
                              void* d_out, int out_size, void* d_ws, size_t ws_size,
                              hipStream_t stream) {
    const float* x   = (const float*)d_in[0];
    const int*   src = (const int*)d_in[1];
    const int*   dst = (const int*)d_in[2];
    const float* Wl0 = (const float*)d_in[3];
    const float* bl0 = (const float*)d_in[4];
    const float* Wr0 = (const float*)d_in[5];
    const float* Wl1 = (const float*)d_in[6];
    const float* bl1 = (const float*)d_in[7];
    const float* Wr1 = (const float*)d_in[8];
    const float* Wl2 = (const float*)d_in[9];
    const float* bl2 = (const float*)d_in[10];
    const float* Wr2 = (const float*)d_in[11];
    float* out = (float*)d_out;

    int N = in_sizes[0] / 128;
    int E = in_sizes[1];
    int nBuckets = (N + 255) >> BUCKET_SHIFT;

    char* ws = (char*)d_ws;
    size_t off = 0;
    auto alloc = [&](size_t bytes) -> char* {
        char* p = ws + off;
        off += (bytes + 255) & ~(size_t)255;
        return p;
    };
    int*   cnt    = (int*)alloc((size_t)N * 4);
    int*   rowptr = (int*)alloc((size_t)(N + 1) * 4);
    float* invd   = (float*)alloc((size_t)N * 4);
    int*   ssrc   = (int*)alloc((size_t)E * 4);
    u16*   xb     = (u16*)alloc((size_t)N * 128 * 2);   // layer0 in, layer1 out, gemmG in
    u16*   h1     = (u16*)alloc((size_t)N * 128 * 2);   // layer0 out, layer1 in
    u16*   Gn     = (u16*)alloc((size_t)N * 64 * 2);    // neighbor projection (layer 2)
    u16*   Gs     = (u16*)alloc((size_t)N * 64 * 2);    // self projection (layer 2)
    int*   bsum   = (int*)alloc(256 * 4);
    int*   gcur   = (int*)alloc(512 * 4);
    u16*   wf0    = (u16*)alloc(32768 * 2);
    u16*   wf1    = (u16*)alloc(32768 * 2);
    u16*   wf2    = (u16*)alloc(16384 * 2);

    // interm (E uints = 6.4 MB) aliases Gn+Gs (25.6 MB): consumed by bucket_sort
    // long before gemmG writes Gn/Gs.
    unsigned* interm = (unsigned*)Gn;

    int nScanBlocks = (N + 2047) / 2048;

    hipMemsetAsync(cnt, 0, (size_t)N * 4, stream);
    hist_kernel<<<(E + 255) / 256, 256, 0, stream>>>(dst, cnt, E);
    block_sum_kernel<<<nScanBlocks, 256, 0, stream>>>(cnt, bsum, N);
    scan_bsum_kernel<<<1, 64, 0, stream>>>(bsum, nScanBlocks);
    scan_write_kernel<<<nScanBlocks, 256, 0, stream>>>(cnt, bsum, rowptr, invd, N);
    init_gcursor_kernel<<<(nBuckets + 255) / 256, 256, 0, stream>>>(rowptr, gcur, nBuckets);
    bucket_scatter_kernel<<<(E + 16383) / 16384, 256, 0, stream>>>(src, dst, gcur, interm,
                                                                   E, nBuckets);
    bucket_sort_kernel<<<nBuckets, 256, 0, stream>>>(interm, rowptr, ssrc, N);
    long total8 = (long)N * 16;  // N*128/8
    convert_kernel<<<(int)((total8 + 255) / 256), 256, 0, stream>>>(x, xb, total8);
    pack01_kernel<<<128, 256, 0, stream>>>(Wl0, Wr0, wf0);
    pack01_kernel<<<128, 256, 0, stream>>>(Wl1, Wr1, wf1);
    packl2_kernel<<<64, 256, 0, stream>>>(Wl2, Wr2, wf2);

    int gemmGrid = (N + 31) / 32;

    // layer 0: xb -> h1 (fused gather-agg + MFMA)
    sage_layer_mfma<<<gemmGrid, 256, 0, stream>>>((const uint2*)xb, rowptr, ssrc, invd,
                                                  wf0, bl0, h1, N);
    // layer 1: h1 -> xb (ping-pong; xb no longer needed as layer-0 input)
    sage_layer_mfma<<<gemmGrid, 256, 0, stream>>>((const uint2*)h1, rowptr, ssrc, invd,
                                                  wf1, bl1, xb, N);
    // layer 2: [Gn|Gs] = xb @ Wp, then 64-wide line gather + log_softmax
    gemmG_mfma<<<gemmGrid, 256, 0, stream>>>(xb, wf2, Gn, Gs, N);
    out_kernel<<<(N + 3) / 4, 256, 0, stream>>>(Gn, Gs, rowptr, ssrc, invd, bl2, out, N);
}

// Round 9
// 444.242 us; speedup vs baseline: 2.8660x; 1.1185x over previous
//
#include <hip/hip_runtime.h>
#include <math.h>

#define BUCKET_SHIFT 8  // 256 nodes per bucket
#define MAX_BE 2048     // max staged edges per sage block

typedef short s8v __attribute__((ext_vector_type(8)));   // 8 bf16 (4 VGPRs)
typedef float f4v __attribute__((ext_vector_type(4)));   // 4 fp32 acc
typedef unsigned short u16;

__device__ inline u16 f2bf(float f) {  // RNE fp32->bf16
    unsigned u = __float_as_uint(f);
    return (u16)((u + 0x7FFFu + ((u >> 16) & 1u)) >> 16);
}
__device__ inline float bf2f(u16 s) { return __uint_as_float(((unsigned)s) << 16); }

// ---------------- CSR build (bucketed, no per-node global atomics) ----------------

// Pass 1: per-chunk LDS bucket histogram -> global bucket counts.
__global__ __launch_bounds__(256) void bucket_count_kernel(const int* __restrict__ dst,
                                                           int* __restrict__ bucketCnt,
                                                           int n_edges, int nbuckets) {
    __shared__ int hist[512];
    int tid = threadIdx.x;
    for (int j = tid; j < nbuckets; j += 256) hist[j] = 0;
    __syncthreads();
    int e0 = blockIdx.x * 16384;
    int e1 = min(e0 + 16384, n_edges);
    for (int e = e0 + tid; e < e1; e += 256)
        atomicAdd(&hist[dst[e] >> BUCKET_SHIFT], 1);
    __syncthreads();
    for (int j = tid; j < nbuckets; j += 256) {
        int c = hist[j];
        if (c > 0) atomicAdd(&bucketCnt[j], c);
    }
}

// Pass 2: one-block parallel exclusive scan of bucket counts -> bucketBase, gcursor.
__global__ __launch_bounds__(512) void scan_buckets_kernel(const int* __restrict__ bucketCnt,
                                                           int* __restrict__ bucketBase,
                                                           int* __restrict__ gcursor,
                                                           int nbuckets) {
    int tid = threadIdx.x;
    int c = (tid < nbuckets) ? bucketCnt[tid] : 0;
    int lane = tid & 63, wave = tid >> 6;
    int v = c;
#pragma unroll
    for (int off = 1; off < 64; off <<= 1) {
        int t = __shfl_up(v, off, 64);
        if (lane >= off) v += t;
    }
    __shared__ int wsum[8], woff[8];
    if (lane == 63) wsum[wave] = v;
    __syncthreads();
    if (tid == 0) {
        int run = 0;
#pragma unroll
        for (int w = 0; w < 8; ++w) { woff[w] = run; run += wsum[w]; }
    }
    __syncthreads();
    int excl = woff[wave] + (v - c);
    if (tid <= nbuckets) bucketBase[tid] = excl;  // tid==nbuckets -> total E
    if (tid < nbuckets) gcursor[tid] = excl;
}

// Pass 3: chunk-per-block; per-bucket contiguous reservations so each block's
// intermediate writes form single-XCD runs. interm = (src << 8) | (dst & 255).
__global__ __launch_bounds__(256) void bucket_scatter_kernel(const int* __restrict__ src,
                                                             const int* __restrict__ dst,
                                                             int* __restrict__ gcursor,
                                                             unsigned* __restrict__ interm,
                                                             int n_edges, int nbuckets) {
    __shared__ int hist[512];
    __shared__ int gbase[512];
    int tid = threadIdx.x;
    for (int j = tid; j < nbuckets; j += 256) hist[j] = 0;
    __syncthreads();
    int e0 = blockIdx.x * 16384;
    int e1 = min(e0 + 16384, n_edges);
    for (int e = e0 + tid; e < e1; e += 256)
        atomicAdd(&hist[dst[e] >> BUCKET_SHIFT], 1);
    __syncthreads();
    for (int j = tid; j < nbuckets; j += 256) {
        int c = hist[j];
        gbase[j] = c > 0 ? atomicAdd(&gcursor[j], c) : 0;
        hist[j] = 0;
    }
    __syncthreads();
    for (int e = e0 + tid; e < e1; e += 256) {
        int d = dst[e];
        int s = src[e];
        int j = d >> BUCKET_SHIFT;
        int p = atomicAdd(&hist[j], 1);
        interm[gbase[j] + p] = ((unsigned)s << 8) | (unsigned)(d & 255);
    }
}

// Pass 4: one block per bucket. Builds per-node counts (LDS), block-scans them to
// produce rowptr + invd, then scatters src ids into the bucket's contiguous ssrc run.
__global__ __launch_bounds__(256) void bucket_build_kernel(const unsigned* __restrict__ interm,
                                                           const int* __restrict__ bucketBase,
                                                           int* __restrict__ rowptr,
                                                           float* __restrict__ invd,
                                                           int* __restrict__ ssrc, int n_nodes) {
    __shared__ int cnt[256];
    __shared__ int cur[256];
    __shared__ int wsum[4], woff[4];
    int tid = threadIdx.x;
    int nb0 = blockIdx.x << BUCKET_SHIFT;
    int base = bucketBase[blockIdx.x];
    int end = bucketBase[blockIdx.x + 1];
    cnt[tid] = 0;
    __syncthreads();
    for (int e = base + tid; e < end; e += 256)
        atomicAdd(&cnt[interm[e] & 255u], 1);
    __syncthreads();
    int c = cnt[tid];
    int lane = tid & 63, wave = tid >> 6;
    int v = c;
#pragma unroll
    for (int off = 1; off < 64; off <<= 1) {
        int t = __shfl_up(v, off, 64);
        if (lane >= off) v += t;
    }
    if (lane == 63) wsum[wave] = v;
    __syncthreads();
    if (tid == 0) {
        int run = 0;
#pragma unroll
        for (int w = 0; w < 4; ++w) { woff[w] = run; run += wsum[w]; }
    }
    __syncthreads();
    int excl = woff[wave] + (v - c);
    int node = nb0 + tid;
    if (node < n_nodes) {
        rowptr[node] = base + excl;
        invd[node] = c > 0 ? 1.0f / (float)c : 0.0f;
        if (node == n_nodes - 1) rowptr[n_nodes] = base + excl + c;
    }
    cur[tid] = base + excl;
    __syncthreads();
    for (int e = base + tid; e < end; e += 256) {
        unsigned p = interm[e];
        int pos = atomicAdd(&cur[p & 255u], 1);
        ssrc[pos] = (int)(p >> 8);
    }
}

// ---------------- x -> bf16 ----------------
__global__ __launch_bounds__(256) void convert_kernel(const float* __restrict__ x,
                                                      u16* __restrict__ xb, long total8) {
    long i = (long)blockIdx.x * 256 + threadIdx.x;
    if (i >= total8) return;
    const float* p = &x[i * 8];
    float4 lo = *(const float4*)p;
    float4 hi = *(const float4*)(p + 4);
    union { u16 u[8]; s8v v; } t;
    t.u[0] = f2bf(lo.x); t.u[1] = f2bf(lo.y); t.u[2] = f2bf(lo.z); t.u[3] = f2bf(lo.w);
    t.u[4] = f2bf(hi.x); t.u[5] = f2bf(hi.y); t.u[6] = f2bf(hi.z); t.u[7] = f2bf(hi.w);
    *(s8v*)&xb[i * 8] = t.v;
}

// ---------------- weight packing into MFMA fragment order ----------------
__global__ void pack01_kernel(const float* __restrict__ Wl, const float* __restrict__ Wr,
                              u16* __restrict__ out) {
    int idx = blockIdx.x * 256 + threadIdx.x;  // 256*128
    if (idx >= 32768) return;
    int k = idx >> 7, c = idx & 127;
    float v = (k < 128) ? Wl[k * 128 + c] : Wr[(k - 128) * 128 + c];
    int kt = k >> 5, q = (k >> 3) & 3, j = k & 7, ct = c >> 4, n = c & 15;
    out[(((kt * 8 + ct) * 64 + q * 16 + n) << 3) + j] = f2bf(v);
}

__global__ void packl2_kernel(const float* __restrict__ Wl, const float* __restrict__ Wr,
                              u16* __restrict__ out) {
    int idx = blockIdx.x * 256 + threadIdx.x;  // 128*128
    if (idx >= 16384) return;
    int k = idx >> 7, c = idx & 127;
    float v = 0.f;
    if (c < 47) v = Wl[k * 47 + c];
    else if (c >= 64 && c < 111) v = Wr[k * 47 + (c - 64)];
    int kt = k >> 5, q = (k >> 3) & 3, j = k & 7, ct = c >> 4, n = c & 15;
    out[(((kt * 8 + ct) * 64 + q * 16 + n) << 3) + j] = f2bf(v);
}

// ---------------- fused SAGE layer: LDS edge staging -> gather-agg -> MFMA ----------------
// hout = relu([mean_agg(hin) | hin] @ Wfrag + b). hin/hout distinct buffers.
__global__ __launch_bounds__(256) void sage_layer_mfma(const uint2* __restrict__ hin2,
                                                       const int* __restrict__ rowptr,
                                                       const int* __restrict__ ssrc,
                                                       const float* __restrict__ invd,
                                                       const u16* __restrict__ Wfrag,
                                                       const float* __restrict__ bias,
                                                       u16* __restrict__ hout, int n_nodes) {
    __shared__ u16 As[32][264];
    __shared__ int eloc[MAX_BE];
    __shared__ int rp[33];
    int tid = threadIdx.x;
    int n0 = blockIdx.x * 32;
    if (tid < 33) rp[tid] = rowptr[min(n0 + tid, n_nodes)];
    __syncthreads();
    int base = rp[0];
    int nE = rp[32] - base;
    bool staged = nE <= MAX_BE;
    if (staged) {
        for (int i = tid; i < nE; i += 256) eloc[i] = ssrc[base + i];  // coalesced
    }
    __syncthreads();

    int d = tid & 31, grp = tid >> 5;  // 8 groups of 32 lanes

    // phase 1: gather-aggregate rows n0..n0+31 into As cols 0..127 (bf16)
#pragma unroll
    for (int pass = 0; pass < 4; ++pass) {
        int row = pass * 8 + grp;
        int n = n0 + row;
        float a0 = 0.f, a1 = 0.f, a2 = 0.f, a3 = 0.f;
        int e = rp[row] - base, e1 = rp[row + 1] - base;
        if (staged) {
            for (; e + 7 < e1; e += 8) {
                int s[8];
#pragma unroll
                for (int j = 0; j < 8; ++j) s[j] = eloc[e + j];
                uint2 vv[8];
#pragma unroll
                for (int j = 0; j < 8; ++j) vv[j] = hin2[(size_t)s[j] * 32 + d];
#pragma unroll
                for (int j = 0; j < 8; ++j) {
                    a0 += __uint_as_float(vv[j].x << 16);
                    a1 += __uint_as_float(vv[j].x & 0xffff0000u);
                    a2 += __uint_as_float(vv[j].y << 16);
                    a3 += __uint_as_float(vv[j].y & 0xffff0000u);
                }
            }
            for (; e < e1; ++e) {
                uint2 vv = hin2[(size_t)eloc[e] * 32 + d];
                a0 += __uint_as_float(vv.x << 16);
                a1 += __uint_as_float(vv.x & 0xffff0000u);
                a2 += __uint_as_float(vv.y << 16);
                a3 += __uint_as_float(vv.y & 0xffff0000u);
            }
        } else {
            for (; e + 7 < e1; e += 8) {
                int s[8];
#pragma unroll
                for (int j = 0; j < 8; ++j) s[j] = ssrc[base + e + j];
                uint2 vv[8];
#pragma unroll
                for (int j = 0; j < 8; ++j) vv[j] = hin2[(size_t)s[j] * 32 + d];
#pragma unroll
                for (int j = 0; j < 8; ++j) {
                    a0 += __uint_as_float(vv[j].x << 16);
                    a1 += __uint_as_float(vv[j].x & 0xffff0000u);
                    a2 += __uint_as_float(vv[j].y << 16);
                    a3 += __uint_as_float(vv[j].y & 0xffff0000u);
                }
            }
            for (; e < e1; ++e) {
                uint2 vv = hin2[(size_t)ssrc[base + e] * 32 + d];
                a0 += __uint_as_float(vv.x << 16);
                a1 += __uint_as_float(vv.x & 0xffff0000u);
                a2 += __uint_as_float(vv.y << 16);
                a3 += __uint_as_float(vv.y & 0xffff0000u);
            }
        }
        float w = (n < n_nodes) ? invd[n] : 0.f;
        a0 *= w; a1 *= w; a2 *= w; a3 *= w;
        uint2 o;
        o.x = (unsigned)f2bf(a0) | ((unsigned)f2bf(a1) << 16);
        o.y = (unsigned)f2bf(a2) | ((unsigned)f2bf(a3) << 16);
        *(uint2*)&As[row][d * 4] = o;
    }

    // phase 2: stage self rows into As cols 128..255
    const u16* hin = (const u16*)hin2;
    for (int i = tid; i < 512; i += 256) {
        int row = i >> 4, c8 = i & 15;
        int n = n0 + row;
        s8v t = (s8v){0, 0, 0, 0, 0, 0, 0, 0};
        if (n < n_nodes) t = *(const s8v*)&hin[(size_t)n * 128 + c8 * 8];
        *(s8v*)&As[row][128 + c8 * 8] = t;
    }
    __syncthreads();

    // phase 3: MFMA, K=256
    int wave = tid >> 6, lane = tid & 63;
    int rt = wave & 1, ch = wave >> 1;
    int m = lane & 15, q = lane >> 4;

    f4v acc[4];
#pragma unroll
    for (int c = 0; c < 4; ++c) acc[c] = (f4v){0.f, 0.f, 0.f, 0.f};

#pragma unroll
    for (int kt = 0; kt < 8; ++kt) {
        s8v a = *(const s8v*)&As[rt * 16 + m][kt * 32 + q * 8];
#pragma unroll
        for (int c = 0; c < 4; ++c) {
            int ctg = ch * 4 + c;
            s8v b = *(const s8v*)&Wfrag[(((size_t)kt * 8 + ctg) * 64 + lane) * 8];
            acc[c] = __builtin_amdgcn_mfma_f32_16x16x32_bf16(a, b, acc[c], 0, 0, 0);
        }
    }

#pragma unroll
    for (int c = 0; c < 4; ++c) {
        int col = ch * 64 + c * 16 + m;
        float bc = bias[col];
#pragma unroll
        for (int r = 0; r < 4; ++r) {
            int n = n0 + rt * 16 + q * 4 + r;
            if (n < n_nodes)
                hout[(size_t)n * 128 + col] = f2bf(fmaxf(acc[c][r] + bc, 0.f));
        }
    }
}

// ---------------- MFMA GEMM: [Gn|Gs] = h @ Wfrag2 bf16, K=128 ----------------
__global__ __launch_bounds__(256) void gemmG_mfma(const u16* __restrict__ h,
                                                  const u16* __restrict__ Wfrag,
                                                  u16* __restrict__ Gn,
                                                  u16* __restrict__ Gs, int n_nodes) {
    __shared__ u16 As[32][136];
    int tid = threadIdx.x;
    int n0 = blockIdx.x * 32;
    for (int i = tid; i < 512; i += 256) {
        int row = i >> 4, c8 = i & 15;
        int n = n0 + row;
        s8v t = (s8v){0, 0, 0, 0, 0, 0, 0, 0};
        if (n < n_nodes) t = *(const s8v*)&h[(size_t)n * 128 + c8 * 8];
        *(s8v*)&As[row][c8 * 8] = t;
    }
    __syncthreads();

    int wave = tid >> 6, lane = tid & 63;
    int rt = wave & 1, ch = wave >> 1;
    int m = lane & 15, q = lane >> 4;

    f4v acc[4];
#pragma unroll
    for (int c = 0; c < 4; ++c) acc[c] = (f4v){0.f, 0.f, 0.f, 0.f};

#pragma unroll
    for (int kt = 0; kt < 4; ++kt) {
        s8v a = *(const s8v*)&As[rt * 16 + m][kt * 32 + q * 8];
#pragma unroll
        for (int c = 0; c < 4; ++c) {
            int ctg = ch * 4 + c;
            s8v b = *(const s8v*)&Wfrag[(((size_t)kt * 8 + ctg) * 64 + lane) * 8];
            acc[c] = __builtin_amdgcn_mfma_f32_16x16x32_bf16(a, b, acc[c], 0, 0, 0);
        }
    }

    u16* Gbase = (ch == 0) ? Gn : Gs;
#pragma unroll
    for (int c = 0; c < 4; ++c) {
        int col = c * 16 + m;
#pragma unroll
        for (int r = 0; r < 4; ++r) {
            int n = n0 + rt * 16 + q * 4 + r;
            if (n < n_nodes) Gbase[(size_t)n * 64 + col] = f2bf(acc[c][r]);
        }
    }
}

// ---------------- layer-2 epilogue: gather Gn (one 128B line/edge) + log_softmax ----------------
__global__ __launch_bounds__(256) void out_kernel(const u16* __restrict__ Gn,
                                                  const u16* __restrict__ Gs,
                                                  const int* __restrict__ rowptr,
                                                  const int* __restrict__ ssrc,
                                                  const float* __restrict__ inv_deg,
                                                  const float* __restrict__ bias,
                                                  float* __restrict__ out, int n_nodes) {
    int lane = threadIdx.x & 63;
    int n = blockIdx.x * 4 + (threadIdx.x >> 6);
    if (n >= n_nodes) return;
    bool ok = lane < 47;
    int e0 = rowptr[n], e1 = rowptr[n + 1];
    float acc = 0.f;
    int e = e0;
    for (; e + 7 < e1; e += 8) {
        int s[8];
#pragma unroll
        for (int j = 0; j < 8; ++j) s[j] = ssrc[e + j];
        float g[8];
#pragma unroll
        for (int j = 0; j < 8; ++j) g[j] = bf2f(Gn[(size_t)s[j] * 64 + lane]);
#pragma unroll
        for (int j = 0; j < 8; ++j) acc += g[j];
    }
    for (; e < e1; ++e) acc += bf2f(Gn[(size_t)ssrc[e] * 64 + lane]);

    float v = -INFINITY;
    if (ok) v = acc * inv_deg[n] + bf2f(Gs[(size_t)n * 64 + lane]) + bias[lane];

    float m = v;
#pragma unroll
    for (int off = 32; off >= 1; off >>= 1)
        m = fmaxf(m, __shfl_xor(m, off, 64));
    float s = ok ? __expf(v - m) : 0.f;
#pragma unroll
    for (int off = 32; off >= 1; off >>= 1)
        s += __shfl_xor(s, off, 64);
    float ls = __logf(s);
    if (ok) out[(size_t)n * 47 + lane] = v - m - ls;
}

// ---------------- launch ----------------

extern "C" void kernel_launch(void* const* d_in, const int* in_sizes, int n_in,
                              void* d_out, int out_size, void* d_ws, size_t ws_size,
                              hipStream_t stream) {
    const float* x   = (const float*)d_in[0];
    const int*   src = (const int*)d_in[1];
    const int*   dst = (const int*)d_in[2];
    const float* Wl0 = (const float*)d_in[3];
    const float* bl0 = (const float*)d_in[4];
    const float* Wr0 = (const float*)d_in[5];
    const float* Wl1 = (const float*)d_in[6];
    const float* bl1 = (const float*)d_in[7];
    const float* Wr1 = (const float*)d_in[8];
    const float* Wl2 = (const float*)d_in[9];
    const float* bl2 = (const float*)d_in[10];
    const float* Wr2 = (const float*)d_in[11];
    float* out = (float*)d_out;

    int N = in_sizes[0] / 128;
    int E = in_sizes[1];
    int nBuckets = (N + 255) >> BUCKET_SHIFT;

    char* ws = (char*)d_ws;
    size_t off = 0;
    auto alloc = [&](size_t bytes) -> char* {
        char* p = ws + off;
        off += (bytes + 255) & ~(size_t)255;
        return p;
    };
    int*   rowptr = (int*)alloc((size_t)(N + 1) * 4);
    float* invd   = (float*)alloc((size_t)N * 4);
    int*   ssrc   = (int*)alloc((size_t)E * 4);
    u16*   xb     = (u16*)alloc((size_t)N * 128 * 2);   // layer0 in, layer1 out, gemmG in
    u16*   h1     = (u16*)alloc((size_t)N * 128 * 2);   // layer0 out, layer1 in
    u16*   Gn     = (u16*)alloc((size_t)N * 64 * 2);    // neighbor projection (layer 2)
    u16*   Gs     = (u16*)alloc((size_t)N * 64 * 2);    // self projection (layer 2)
    int*   bucketCnt  = (int*)alloc(512 * 4);
    int*   bucketBase = (int*)alloc(520 * 4);
    int*   gcur   = (int*)alloc(512 * 4);
    u16*   wf0    = (u16*)alloc(32768 * 2);
    u16*   wf1    = (u16*)alloc(32768 * 2);
    u16*   wf2    = (u16*)alloc(16384 * 2);

    // interm (E uints = 6.4 MB) aliases Gn+Gs (25.6 MB): consumed by bucket_build
    // long before gemmG writes Gn/Gs.
    unsigned* interm = (unsigned*)Gn;

    int nChunks = (E + 16383) / 16384;

    hipMemsetAsync(bucketCnt, 0, 512 * 4, stream);
    bucket_count_kernel<<<nChunks, 256, 0, stream>>>(dst, bucketCnt, E, nBuckets);
    scan_buckets_kernel<<<1, 512, 0, stream>>>(bucketCnt, bucketBase, gcur, nBuckets);
    bucket_scatter_kernel<<<nChunks, 256, 0, stream>>>(src, dst, gcur, interm, E, nBuckets);
    bucket_build_kernel<<<nBuckets, 256, 0, stream>>>(interm, bucketBase, rowptr, invd,
                                                      ssrc, N);
    long total8 = (long)N * 16;  // N*128/8
    convert_kernel<<<(int)((total8 + 255) / 256), 256, 0, stream>>>(x, xb, total8);
    pack01_kernel<<<128, 256, 0, stream>>>(Wl0, Wr0, wf0);
    pack01_kernel<<<128, 256, 0, stream>>>(Wl1, Wr1, wf1);
    packl2_kernel<<<64, 256, 0, stream>>>(Wl2, Wr2, wf2);

    int gemmGrid = (N + 31) / 32;

    // layer 0: xb -> h1 (fused gather-agg + MFMA)
    sage_layer_mfma<<<gemmGrid, 256, 0, stream>>>((const uint2*)xb, rowptr, ssrc, invd,
                                                  wf0, bl0, h1, N);
    // layer 1: h1 -> xb (ping-pong)
    sage_layer_mfma<<<gemmGrid, 256, 0, stream>>>((const uint2*)h1, rowptr, ssrc, invd,
                                                  wf1, bl1, xb, N);
    // layer 2: [Gn|Gs] = xb @ Wp, then 64-wide line gather + log_softmax
    gemmG_mfma<<<gemmGrid, 256, 0, stream>>>(xb, wf2, Gn, Gs, N);
    out_kernel<<<(N + 3) / 4, 256, 0, stream>>>(Gn, Gs, rowptr, ssrc, invd, bl2, out, N);
}